// Round 7
// baseline (488.798 us; speedup 1.0000x reference)
//
#include <hip/hip_runtime.h>
#include <hip/hip_bf16.h>
#include <math.h>

#define D_  256
#define T_  2048
#define B_  4
#define M_  (B_*T_)
#define H_  4
#define HD_ 64

#define NC_ 64          // scan chunks
#define LCH (T_/NC_)    // 32 steps per chunk

enum { OP_NONE=0, OP_SIGMUL=1, OP_ADDAUX=2, OP_AXPBY=3, OP_GELU=4, OP_TANHHALF=5 };

typedef unsigned short u16;
typedef short short8 __attribute__((ext_vector_type(8)));
typedef float f32x4  __attribute__((ext_vector_type(4)));

__device__ __forceinline__ float gelu_f(float x){ return 0.5f*x*(1.0f+erff(x*0.70710678118654752f)); }
__device__ __forceinline__ float sigmoid_f(float x){ return 1.0f/(1.0f+expf(-x)); }

__device__ __forceinline__ unsigned pk2(float a, float b){
    __hip_bfloat162 h = __float22bfloat162_rn(make_float2(a,b));
    union { __hip_bfloat162 h; unsigned u; } c; c.h = h; return c.u;
}
__device__ __forceinline__ float bfu(u16 u){ return __uint_as_float(((unsigned)u)<<16); }
__device__ __forceinline__ u16 bf1(float x){ return (u16)(pk2(x,x)&0xffffu); }

// weight-pack element offsets inside Wh (u16 elements)
#define OFF_QKV   0u        // fused qkv(768)+gkv(512) rows -> [1280,256]
#define OFF_MO    327680u
#define OFF_FG    393216u
#define OFF_GO    524288u
#define OFF_COMB  589824u
#define OFF_FFN1  786432u
#define OFF_FFN2  1048576u
#define OFF_TR1   1310720u
#define OFF_TR2   1572864u
#define OFF_P2S   1703936u
#define OFF_S2P   1769472u
#define NWELEM    1835008u
#define NXELEM    2097152u

// ---------------------------------------------------------------------------
// One-shot fp32 -> bf16 conversion of all weights + X, and qkv/gkv bias concat.
// ---------------------------------------------------------------------------
__global__ __launch_bounds__(256) void cvt_k(
    const float* __restrict__ qkv_w, const float* __restrict__ gkv_w,
    const float* __restrict__ qkv_b, const float* __restrict__ gkv_b,
    const float* __restrict__ mo_w,  const float* __restrict__ fg_w,
    const float* __restrict__ go_w,  const float* __restrict__ comb_w,
    const float* __restrict__ ffn1_w,const float* __restrict__ ffn2_w,
    const float* __restrict__ tr1_w, const float* __restrict__ tr2_w,
    const float* __restrict__ p2s_w, const float* __restrict__ s2p_w,
    const float* __restrict__ X,
    u16* __restrict__ Wh, u16* __restrict__ Xh, float* __restrict__ bq)
{
    size_t i = ((size_t)blockIdx.x*256 + threadIdx.x)*4;
    if (i < NWELEM){
        const float* s; size_t base;
        if      (i < OFF_MO)  { s=(i<196608)?qkv_w:gkv_w; base=(i<196608)?0:196608; }
        else if (i < OFF_FG)  { s=mo_w;   base=OFF_MO; }
        else if (i < OFF_GO)  { s=fg_w;   base=OFF_FG; }
        else if (i < OFF_COMB){ s=go_w;   base=OFF_GO; }
        else if (i < OFF_FFN1){ s=comb_w; base=OFF_COMB; }
        else if (i < OFF_FFN2){ s=ffn1_w; base=OFF_FFN1; }
        else if (i < OFF_TR1) { s=ffn2_w; base=OFF_FFN2; }
        else if (i < OFF_TR2) { s=tr1_w;  base=OFF_TR1; }
        else if (i < OFF_P2S) { s=tr2_w;  base=OFF_TR2; }
        else if (i < OFF_S2P) { s=p2s_w;  base=OFF_P2S; }
        else                  { s=s2p_w;  base=OFF_S2P; }
        float4 v = *(const float4*)(s + (i-base));
        *(uint2*)(Wh + i) = (uint2){ pk2(v.x,v.y), pk2(v.z,v.w) };
    } else if (i < NWELEM + NXELEM){
        size_t j = i - NWELEM;
        float4 v = *(const float4*)(X + j);
        *(uint2*)(Xh + j) = (uint2){ pk2(v.x,v.y), pk2(v.z,v.w) };
    } else if (i < NWELEM + NXELEM + 1280){
        size_t j = i - (NWELEM + NXELEM);
        #pragma unroll
        for (int k=0;k<4;++k){
            size_t e = j + k;
            bq[e] = (e < 768) ? qkv_b[e] : gkv_b[e-768];
        }
    }
}

// ---------------------------------------------------------------------------
// bf16 MFMA GEMM, register-staged pipeline, BK=128 (2 barriers per 128-K).
// Tile 64x64, 4 waves (2x2), mfma_f32_16x16x32_bf16, XCD swizzle.
// ---------------------------------------------------------------------------
__global__ __launch_bounds__(256) void gemm_k(
    const u16* __restrict__ A0, const u16* __restrict__ W0, int ldw0, int K0,
    const u16* __restrict__ A1, const u16* __restrict__ W1, int ldw1, int K1,
    const u16* __restrict__ A2, const u16* __restrict__ W2, int ldw2, int K2,
    const float* __restrict__ bias, const void* __restrict__ aux, int aux_bf16,
    void* __restrict__ C, int ldc, int c_bf16, int op, int ncol)
{
    __shared__ u16 As[64*128];
    __shared__ u16 Ws[64*128];

    const int q8   = gridDim.x >> 3;
    const int lid  = (blockIdx.x & 7)*q8 + (blockIdx.x >> 3);
    const int brow = lid / ncol;
    const int bcol = lid - brow*ncol;
    const int row0 = brow*64, col0 = bcol*64;

    const int tid  = threadIdx.x;
    const int lane = tid & 63, wid = tid >> 6;
    const int wm = (wid >> 1)*32, wn = (wid & 1)*32;
    const int l15 = lane & 15, l4 = lane >> 4;
    const int srow = tid >> 2;          // 0..63
    const int sc   = (tid & 3) * 32;    // k-offset within BK=128

    f32x4 acc[2][2];
    #pragma unroll
    for (int i=0;i<2;++i)
        #pragma unroll
        for (int j=0;j<2;++j) acc[i][j] = (f32x4){0.f,0.f,0.f,0.f};

    uint4 ra[4], rw[4];

    auto loadtile = [&](const u16* A, const u16* W, int ldw, int K, int kb){
        const u16* ga = A + (size_t)(row0+srow)*K + kb + sc;
        const u16* gw = W + (size_t)(col0+srow)*ldw + kb + sc;
        #pragma unroll
        for (int c=0;c<4;++c){ ra[c] = *(const uint4*)(ga + c*8); rw[c] = *(const uint4*)(gw + c*8); }
    };
    auto storetile = [&](){
        #pragma unroll
        for (int c=0;c<4;++c){
            const int idx = (srow*128 + sc + c*8) ^ ((srow&15)<<3);
            *(uint4*)&As[idx] = ra[c];
            *(uint4*)&Ws[idx] = rw[c];
        }
    };
    auto mfma_tile = [&](){
        #pragma unroll
        for (int ks=0;ks<4;++ks){
            const int koff = ks*32 + l4*8;
            short8 af[2], bf[2];
            #pragma unroll
            for (int f=0;f<2;++f){
                const int ar = wm + f*16 + l15;
                af[f] = *(const short8*)&As[(ar*128 + koff) ^ ((ar&15)<<3)];
                const int brn = wn + f*16 + l15;
                bf[f] = *(const short8*)&Ws[(brn*128 + koff) ^ ((brn&15)<<3)];
            }
            #pragma unroll
            for (int fm=0;fm<2;++fm)
                #pragma unroll
                for (int fn=0;fn<2;++fn)
                    acc[fm][fn] = __builtin_amdgcn_mfma_f32_16x16x32_bf16(
                        af[fm], bf[fn], acc[fm][fn], 0, 0, 0);
        }
    };

    const u16* Ac = A0; const u16* Wc = W0; int ldwc = ldw0, Kc = K0, kb = 0;
    loadtile(Ac, Wc, ldwc, Kc, 0);
    while (true){
        __syncthreads();            // drains in-flight loads + LDS free
        storetile();
        __syncthreads();            // staged tile visible
        int nkb = kb + 128;
        const u16* nA = Ac; const u16* nW = Wc; int nld = ldwc, nK = Kc;
        bool have_next = true;
        if (nkb >= Kc){
            if (Ac == A0 && A1){ nA = A1; nW = W1; nld = ldw1; nK = K1; nkb = 0; }
            else if (Ac == A1 && A2){ nA = A2; nW = W2; nld = ldw2; nK = K2; nkb = 0; }
            else have_next = false;
        }
        if (have_next) loadtile(nA, nW, nld, nK, nkb);   // in flight across MFMA
        mfma_tile();
        if (!have_next) break;
        Ac = nA; Wc = nW; ldwc = nld; Kc = nK; kb = nkb;
    }

    #pragma unroll
    for (int fn=0;fn<2;++fn){
        const int n = col0 + wn + fn*16 + l15;
        const float bv = bias[n];
        #pragma unroll
        for (int fm=0;fm<2;++fm){
            #pragma unroll
            for (int j=0;j<4;++j){
                const int m = row0 + wm + fm*16 + l4*4 + j;
                float v = acc[fm][fn][j] + bv;
                if (op==OP_GELU)          v = gelu_f(v);
                else if (op==OP_TANHHALF) v = 0.5f*tanhf(v);
                else if (op!=OP_NONE){
                    const size_t ai = (size_t)m*D_ + n;
                    const float a = aux_bf16 ? bfu(((const u16*)aux)[ai])
                                             : ((const float*)aux)[ai];
                    if (op==OP_SIGMUL)      v = a*sigmoid_f(v);
                    else if (op==OP_ADDAUX) v = v + a;
                    else                    v = a + 0.3f*v;
                }
                if (c_bf16) ((u16*)C)[(size_t)m*ldc + n] = bf1(v);
                else        ((float*)C)[(size_t)m*ldc + n] = v;
            }
        }
    }
}

// ---------------------------------------------------------------------------
// Depthwise causal conv, K=8, pad left 7. bf16 in, bf16 out.
// ---------------------------------------------------------------------------
__global__ __launch_bounds__(256) void conv_k(const u16* __restrict__ Xh,
    const float* __restrict__ w, const float* __restrict__ bias, u16* __restrict__ out)
{
    int idx = blockIdx.x*256 + threadIdx.x;
    int d = idx & (D_-1);
    int bt = idx >> 8;
    int t = bt & (T_-1);
    float acc = bias[d];
    const u16* xp = Xh + (size_t)bt*D_ + d;
    const float* wp = w + d*8;
    #pragma unroll
    for (int j=0;j<8;++j){
        int tt = t - 7 + j;
        if (tt >= 0) acc += bfu(xp[(size_t)(j-7)*D_]) * wp[j];
    }
    out[idx] = bf1(acc);
}

// ---------------------------------------------------------------------------
// MFMA banded attention. Per block: (b, h, 64-query tile), 4 waves.
// V transposed in-LDS from QKVG (no VT buffer).
// ---------------------------------------------------------------------------
__global__ __launch_bounds__(256) void attn_k(const u16* __restrict__ QKVG,
    u16* __restrict__ MED)
{
    __shared__ u16 Kl[128*64];
    __shared__ u16 Ql[64*64];
    __shared__ u16 Vl[64*128];
    const int b = blockIdx.z, h = blockIdx.y;
    const int t0 = blockIdx.x * 64;
    const int kb0 = t0 - 64;
    const int tid = threadIdx.x;

    {   // stage K (128 key rows x 64 dims), Q (64 rows), V transposed (64 d x 128 k)
        const int r0 = tid >> 3, c8 = (tid & 7) * 8;
        #pragma unroll
        for (int rep=0;rep<4;++rep){
            const int r = r0 + rep*32;
            const int kg = kb0 + r;
            uint4 pk = {0,0,0,0}, pv = {0,0,0,0};
            if (kg >= 0){
                const u16* gp = QKVG + ((size_t)(b*T_ + kg))*1280 + h*HD_ + c8;
                pk = *(const uint4*)(gp + 256);
                pv = *(const uint4*)(gp + 512);
            }
            *(uint4*)&Kl[(r*64 + c8) ^ ((r&7)<<3)] = pk;
            const u16* pvu = (const u16*)&pv;
            #pragma unroll
            for (int j=0;j<8;++j){
                const int d = c8 + j;
                Vl[(d*128 + r) ^ ((d&15)<<3)] = pvu[j];
            }
        }
        #pragma unroll
        for (int rep=0;rep<2;++rep){
            const int r = r0 + rep*32;
            uint4 pq = *(const uint4*)(QKVG + ((size_t)(b*T_ + t0 + r))*1280 + h*HD_ + c8);
            *(uint4*)&Ql[(r*64 + c8) ^ ((r&7)<<3)] = pq;
        }
    }
    __syncthreads();

    const int lane = tid & 63, w = tid >> 6;
    const int l15 = lane & 15, l4 = lane >> 4;

    short8 bq[2];
    {
        const int qr = w*16 + l15;
        bq[0] = *(const short8*)&Ql[(qr*64 +      l4*8) ^ ((qr&7)<<3)];
        bq[1] = *(const short8*)&Ql[(qr*64 + 32 + l4*8) ^ ((qr&7)<<3)];
    }

    f32x4 s[8];
    #pragma unroll
    for (int kf=0;kf<8;++kf){
        const int kr = kf*16 + l15;
        short8 a0 = *(const short8*)&Kl[(kr*64 +      l4*8) ^ ((kr&7)<<3)];
        short8 a1 = *(const short8*)&Kl[(kr*64 + 32 + l4*8) ^ ((kr&7)<<3)];
        f32x4 acc = (f32x4){0.f,0.f,0.f,0.f};
        acc = __builtin_amdgcn_mfma_f32_16x16x32_bf16(a0, bq[0], acc, 0,0,0);
        acc = __builtin_amdgcn_mfma_f32_16x16x32_bf16(a1, bq[1], acc, 0,0,0);
        s[kf] = acc;
    }

    const int qg = t0 + w*16 + l15;
    float m = -1e30f;
    #pragma unroll
    for (int kf=0;kf<8;++kf){
        #pragma unroll
        for (int j=0;j<4;++j){
            const int kg = kb0 + kf*16 + l4*4 + j;
            const int diff = qg - kg;
            const float v = (kg >= 0 && diff >= 0 && diff < 64) ? s[kf][j]*0.125f : -1e30f;
            s[kf][j] = v;
            m = fmaxf(m, v);
        }
    }
    m = fmaxf(m, __shfl_xor(m,16));
    m = fmaxf(m, __shfl_xor(m,32));
    float lsum = 0.f;
    unsigned lo[8], hi[8];
    #pragma unroll
    for (int kf=0;kf<8;++kf){
        const float p0 = expf(s[kf][0]-m), p1 = expf(s[kf][1]-m);
        const float p2 = expf(s[kf][2]-m), p3 = expf(s[kf][3]-m);
        lsum += (p0+p1)+(p2+p3);
        lo[kf] = pk2(p0,p1);
        hi[kf] = pk2(p2,p3);
    }
    lsum += __shfl_xor(lsum,16);
    lsum += __shfl_xor(lsum,32);
    const float inv = 1.f/lsum;

    f32x4 o[4];
    #pragma unroll
    for (int df=0;df<4;++df) o[df] = (f32x4){0.f,0.f,0.f,0.f};
    const int baseLane = l15 + ((l4&1)<<5);
    const bool hiHalf = (l4>>1) != 0;
    #pragma unroll
    for (int kb=0;kb<4;++kb){
        const int x0 = __shfl((int)lo[2*kb],   baseLane);
        const int x1 = __shfl((int)hi[2*kb],   baseLane);
        const int x2 = __shfl((int)lo[2*kb],   baseLane+16);
        const int x3 = __shfl((int)hi[2*kb],   baseLane+16);
        const int y0 = __shfl((int)lo[2*kb+1], baseLane);
        const int y1 = __shfl((int)hi[2*kb+1], baseLane);
        const int y2 = __shfl((int)lo[2*kb+1], baseLane+16);
        const int y3 = __shfl((int)hi[2*kb+1], baseLane+16);
        int4 afi;
        afi.x = hiHalf ? y0 : x0;
        afi.y = hiHalf ? y1 : x1;
        afi.z = hiHalf ? y2 : x2;
        afi.w = hiHalf ? y3 : x3;
        union { int4 i; short8 s; } cv; cv.i = afi;
        #pragma unroll
        for (int df=0;df<4;++df){
            const int vr = df*16 + l15;
            short8 bv = *(const short8*)&Vl[(vr*128 + kb*32 + l4*8) ^ ((vr&15)<<3)];
            o[df] = __builtin_amdgcn_mfma_f32_16x16x32_bf16(cv.s, bv, o[df], 0,0,0);
        }
    }

    #pragma unroll
    for (int j=0;j<4;++j){
        const float invj = __shfl(inv, l4*4 + j);
        const int mrow = b*T_ + t0 + w*16 + l4*4 + j;
        u16* op = MED + (size_t)mrow*D_ + h*HD_ + l15;
        #pragma unroll
        for (int df=0;df<4;++df)
            op[df*16] = bf1(o[df][j] * invj);
    }
}

// ---------------------------------------------------------------------------
// Chunked scans: p1 = per-chunk aggregate; p3 = own prefix + replay (no p2).
// ---------------------------------------------------------------------------
__global__ __launch_bounds__(256) void scan1_p1(const u16* __restrict__ QKVG,
    float* __restrict__ CA, float* __restrict__ CC)
{
    const int d = threadIdx.x, c = blockIdx.x, b = blockIdx.y;
    const u16* base = QKVG + ((size_t)(b*T_ + c*LCH))*1280;
    float sgk=0.f, sgkv=0.f;
    for (int t=0;t<LCH;++t){
        float gk = bfu(base[(size_t)t*1280 + 768 + d]);
        gk = gk > 0.f ? gk + 1.f : expf(gk);
        float gv = bfu(base[(size_t)t*1280 + 1024 + d]);
        sgk += gk; sgkv += gk*gv;
    }
    CA[((size_t)b*NC_ + c)*D_ + d] = sgk;
    CC[((size_t)b*NC_ + c)*D_ + d] = sgkv;
}

__global__ __launch_bounds__(256) void scan1_p3(const u16* __restrict__ QKVG,
    const float* __restrict__ CA, const float* __restrict__ CC, u16* __restrict__ CONC)
{
    const int d = threadIdx.x, c = blockIdx.x, b = blockIdx.y;
    float sgk = 0.f, sgkv = 0.f;
    for (int cc=0; cc<c; ++cc){
        sgk  += CA[((size_t)b*NC_ + cc)*D_ + d];
        sgkv += CC[((size_t)b*NC_ + cc)*D_ + d];
    }
    const u16* base = QKVG + ((size_t)(b*T_ + c*LCH))*1280;
    u16* out = CONC + ((size_t)(b*T_ + c*LCH))*D_ + d;
    for (int t=0;t<LCH;++t){
        float gk = bfu(base[(size_t)t*1280 + 768 + d]);
        gk = gk > 0.f ? gk + 1.f : expf(gk);
        float gv = bfu(base[(size_t)t*1280 + 1024 + d]);
        sgk += gk; sgkv += gk*gv;
        out[(size_t)t*D_] = bf1(sgkv / (sgk + 1e-5f));
    }
}

// EMA p1: bf16 input
__global__ __launch_bounds__(256) void ema_p1h(const u16* __restrict__ X,
    float* __restrict__ CARRY, float alpha)
{
    const int d = threadIdx.x, c = blockIdx.x, b = blockIdx.y;
    const u16* xp = X + ((size_t)(b*T_ + c*LCH))*D_ + d;
    float g = 0.f;
    for (int t=0;t<LCH;++t) g = 0.9f*g + alpha*bfu(xp[(size_t)t*D_]);
    CARRY[((size_t)b*NC_ + c)*D_ + d] = g;
}

// EMA p1: fp32 input
__global__ __launch_bounds__(256) void ema_p1(const float* __restrict__ X,
    float* __restrict__ CARRY, float alpha)
{
    const int d = threadIdx.x, c = blockIdx.x, b = blockIdx.y;
    const float* xp = X + ((size_t)(b*T_ + c*LCH))*D_ + d;
    float g = 0.f;
    for (int t=0;t<LCH;++t) g = 0.9f*g + alpha*xp[(size_t)t*D_];
    CARRY[((size_t)b*NC_ + c)*D_ + d] = g;
}

// EMA replay (bf16 in/out) + own prefix; last chunk writes traj.
__global__ __launch_bounds__(256) void ema_p3h(const u16* __restrict__ X,
    const float* __restrict__ CARRY, u16* __restrict__ OUT, float alpha,
    float* __restrict__ traj)
{
    const int d = threadIdx.x, c = blockIdx.x, b = blockIdx.y;
    const float dL = powf(0.9f, (float)LCH);
    float g = 0.f;
    for (int cc=0; cc<c; ++cc) g = CARRY[((size_t)b*NC_ + cc)*D_ + d] + dL*g;
    const u16* xp = X + ((size_t)(b*T_ + c*LCH))*D_ + d;
    u16* op = OUT + ((size_t)(b*T_ + c*LCH))*D_ + d;
    for (int t=0;t<LCH;++t){
        g = 0.9f*g + alpha*bfu(xp[(size_t)t*D_]);
        op[(size_t)t*D_] = bf1(g);
    }
    if (c == NC_-1) traj[b*D_ + d] = g;
}

// state EMA replay (fp32) + analytic initial decay, own prefix.
__global__ __launch_bounds__(256) void ema_p3_state(const float* __restrict__ X,
    const float* __restrict__ CARRY, const float* __restrict__ SEQ, float* __restrict__ OUT)
{
    const int d = threadIdx.x, c = blockIdx.x, b = blockIdx.y;
    const float dL = powf(0.9f, (float)LCH);
    float a = 0.f;
    for (int cc=0; cc<c; ++cc) a = CARRY[((size_t)b*NC_ + cc)*D_ + d] + dL*a;
    const float ss = SEQ[b*D_ + d];
    float dp = powf(0.9f, (float)(c*LCH + 1));
    const float* xp = X + ((size_t)(b*T_ + c*LCH))*D_ + d;
    float* op = OUT + ((size_t)(b*T_ + c*LCH))*D_ + d;
    for (int t=0;t<LCH;++t){
        a = 0.9f*a + xp[(size_t)t*D_];
        op[(size_t)t*D_] = fmaf(ss, dp, a);
        dp *= 0.9f;
    }
}

// ---------------------------------------------------------------------------
// LayerNorms
// ---------------------------------------------------------------------------
__global__ __launch_bounds__(256) void ln_k(const float* __restrict__ in,
    const float* __restrict__ g, const float* __restrict__ b,
    float* __restrict__ out, u16* __restrict__ out2)
{
    int row  = blockIdx.x*4 + (threadIdx.x>>6);
    int lane = threadIdx.x & 63;
    const float* ip = in + (size_t)row*D_ + lane*4;
    float4 x = *(const float4*)ip;
    float s  = x.x+x.y+x.z+x.w;
    float s2 = x.x*x.x + x.y*x.y + x.z*x.z + x.w*x.w;
    #pragma unroll
    for (int o=1;o<64;o<<=1){ s += __shfl_xor(s,o); s2 += __shfl_xor(s2,o); }
    float mean = s * (1.f/256.f);
    float var  = s2 * (1.f/256.f) - mean*mean;
    float rs = rsqrtf(var + 1e-5f);
    int db = lane*4;
    float4 r;
    r.x=(x.x-mean)*rs*g[db+0]+b[db+0];
    r.y=(x.y-mean)*rs*g[db+1]+b[db+1];
    r.z=(x.z-mean)*rs*g[db+2]+b[db+2];
    r.w=(x.w-mean)*rs*g[db+3]+b[db+3];
    *(float4*)(out + (size_t)row*D_ + db) = r;
    if (out2)
        *(uint2*)(out2 + (size_t)row*D_ + db) = (uint2){ pk2(r.x,r.y), pk2(r.z,r.w) };
}

__global__ __launch_bounds__(256) void ln3_k(const float* __restrict__ in,
    const float* __restrict__ g3, const float* __restrict__ b3, u16* __restrict__ states,
    const float* __restrict__ g4, const float* __restrict__ b4, float* __restrict__ fsout)
{
    int row  = blockIdx.x*4 + (threadIdx.x>>6);
    int lane = threadIdx.x & 63;
    const float* ip = in + (size_t)row*D_ + lane*4;
    float4 x = *(const float4*)ip;
    float s  = x.x+x.y+x.z+x.w;
    float s2 = x.x*x.x + x.y*x.y + x.z*x.z + x.w*x.w;
    #pragma unroll
    for (int o=1;o<64;o<<=1){ s += __shfl_xor(s,o); s2 += __shfl_xor(s2,o); }
    float mean = s * (1.f/256.f);
    float var  = s2 * (1.f/256.f) - mean*mean;
    float rs = rsqrtf(var + 1e-5f);
    int db = lane*4;
    float4 st;
    st.x=(x.x-mean)*rs*g3[db+0]+b3[db+0];
    st.y=(x.y-mean)*rs*g3[db+1]+b3[db+1];
    st.z=(x.z-mean)*rs*g3[db+2]+b3[db+2];
    st.w=(x.w-mean)*rs*g3[db+3]+b3[db+3];
    *(uint2*)(states + (size_t)row*D_ + db) = (uint2){ pk2(st.x,st.y), pk2(st.z,st.w) };

    if ((row & (T_-1)) == T_-1){
        float u  = st.x+st.y+st.z+st.w;
        float u2 = st.x*st.x + st.y*st.y + st.z*st.z + st.w*st.w;
        #pragma unroll
        for (int o=1;o<64;o<<=1){ u += __shfl_xor(u,o); u2 += __shfl_xor(u2,o); }
        float m2 = u * (1.f/256.f);
        float v2 = u2 * (1.f/256.f) - m2*m2;
        float r2 = rsqrtf(v2 + 1e-5f);
        float4 fs;
        fs.x=(st.x-m2)*r2*g4[db+0]+b4[db+0];
        fs.y=(st.y-m2)*r2*g4[db+1]+b4[db+1];
        fs.z=(st.z-m2)*r2*g4[db+2]+b4[db+2];
        fs.w=(st.w-m2)*r2*g4[db+3]+b4[db+3];
        *(float4*)(fsout + (size_t)(row>>11)*D_ + db) = fs;
    }
}

// ---------------------------------------------------------------------------
extern "C" void kernel_launch(void* const* d_in, const int* in_sizes, int n_in,
                              void* d_out, int out_size, void* d_ws, size_t ws_size,
                              hipStream_t stream)
{
    const float* X     = (const float*)d_in[0];
    const float* SEQ   = (const float*)d_in[1];
    const float* conv_w= (const float*)d_in[3];
    const float* conv_b= (const float*)d_in[4];
    const float* qkv_w = (const float*)d_in[5];
    const float* qkv_b = (const float*)d_in[6];
    const float* mo_w  = (const float*)d_in[7];
    const float* mo_b  = (const float*)d_in[8];
    const float* fg_w  = (const float*)d_in[9];
    const float* fg_b  = (const float*)d_in[10];
    const float* gkv_w = (const float*)d_in[11];
    const float* gkv_b = (const float*)d_in[12];
    const float* go_w  = (const float*)d_in[13];
    const float* go_b  = (const float*)d_in[14];
    const float* comb_w= (const float*)d_in[15];
    const float* comb_b= (const float*)d_in[16];
    const float* ffn1_w= (const float*)d_in[17];
    const float* ffn1_b= (const float*)d_in[18];
    const float* ffn2_w= (const float*)d_in[19];
    const float* ffn2_b= (const float*)d_in[20];
    const float* tr1_w = (const float*)d_in[21];
    const float* tr1_b = (const float*)d_in[22];
    const float* tr2_w = (const float*)d_in[23];
    const float* tr2_b = (const float*)d_in[24];
    const float* p2s_w = (const float*)d_in[25];
    const float* p2s_b = (const float*)d_in[26];
    const float* s2p_w = (const float*)d_in[27];
    const float* s2p_b = (const float*)d_in[28];
    const float* ln1_g = (const float*)d_in[29];
    const float* ln1_b = (const float*)d_in[30];
    const float* ln2_g = (const float*)d_in[31];
    const float* ln2_b = (const float*)d_in[32];
    const float* ln3_g = (const float*)d_in[33];
    const float* ln3_b = (const float*)d_in[34];
    const float* ln4_g = (const float*)d_in[35];
    const float* ln4_b = (const float*)d_in[36];

    // -------- workspace carve (256-byte aligned chunks) --------
    char* p = (char*)d_ws;
    auto alloc = [&](size_t bytes)->char*{ char* r = p; p += (bytes + 255) & ~(size_t)255; return r; };

    u16*   QKVG = (u16*)  alloc((size_t)M_*1280*2);
    u16*   Wh   = (u16*)  alloc((size_t)NWELEM*2);
    float* bq   = (float*)alloc(1280*4);
    u16*   Xh   = (u16*)  alloc((size_t)M_*256*2);
    u16*   MED  = (u16*)  alloc((size_t)M_*256*2);
    u16*   MED2 = (u16*)  alloc((size_t)M_*256*2);
    u16*   LH   = (u16*)  alloc((size_t)M_*256*2);
    u16*   CONC = (u16*)  alloc((size_t)M_*256*2);
    u16*   GOUT = (u16*)  alloc((size_t)M_*256*2);
    u16*   MOUT = (u16*)  alloc((size_t)M_*256*2);
    float* PRE1 = (float*)alloc((size_t)M_*256*4);
    float* PR   = (float*)alloc((size_t)M_*256*4);
    u16*   PRh  = (u16*)  alloc((size_t)M_*256*2);
    u16*   GSUM = (u16*)  alloc((size_t)M_*256*2);
    u16*   CS1  = (u16*)  alloc((size_t)M_*256*2);
    u16*   H1   = (u16*)  alloc((size_t)M_*512*2);
    float* SCALED=(float*)alloc((size_t)M_*256*4);
    float* PRE3 = (float*)alloc((size_t)M_*256*4);
    u16*   STATESh=(u16*) alloc((size_t)M_*256*2);
    u16*   FFNIN= (u16*)  alloc((size_t)M_*256*2);
    u16*   H2   = (u16*)  alloc((size_t)M_*1024*2);
    float* PRE2 = (float*)alloc((size_t)M_*256*4);
    float* CAR0 = (float*)alloc((size_t)B_*NC_*D_*4);
    float* CAR1 = (float*)alloc((size_t)B_*NC_*D_*4);

    float* out_pr = (float*)d_out;
    float* out_fs = out_pr + (size_t)M_*256;
    float* out_tj = out_fs + B_*256;

    const dim3 blk256(256);
    const dim3 scan_grid(NC_, B_);
    const int NR = M_/64;   // 128 row tiles

    // 0. convert weights + X to bf16, concat qkv/gkv bias
    cvt_k<<<dim3(3842), blk256, 0, stream>>>(
        qkv_w, gkv_w, qkv_b, gkv_b, mo_w, fg_w, go_w, comb_w,
        ffn1_w, ffn2_w, tr1_w, tr2_w, p2s_w, s2p_w, X, Wh, Xh, bq);
    // 1. fused qkv+gkv projection -> QKVG (bf16)
    gemm_k<<<dim3(NR*20), blk256, 0, stream>>>(
        Xh, Wh+OFF_QKV, 256, 256,  nullptr,nullptr,0,0,  nullptr,nullptr,0,0,
        bq, nullptr, 0, QKVG, 1280, 1, OP_NONE, 20);
    // 2. local_history (depthwise conv) -> LH bf16
    conv_k<<<dim3(M_*D_/256), blk256, 0, stream>>>(Xh, conv_w, conv_b, LH);
    // 3. banded attention (MFMA, V transposed in-LDS) -> MED bf16
    attn_k<<<dim3(T_/64, H_, B_), blk256, 0, stream>>>(QKVG, MED);
    // 4. mo projection -> MED2 bf16
    gemm_k<<<dim3(NR*4), blk256, 0, stream>>>(
        MED, Wh+OFF_MO, 256, 256,  nullptr,nullptr,0,0,  nullptr,nullptr,0,0,
        mo_b, nullptr, 0, MED2, 256, 1, OP_NONE, 4);
    // 5. concepts scan -> CONC bf16
    scan1_p1<<<scan_grid, blk256, 0, stream>>>(QKVG, CAR0, CAR1);
    scan1_p3<<<scan_grid, blk256, 0, stream>>>(QKVG, CAR0, CAR1, CONC);
    // 6. global_out -> GOUT bf16
    gemm_k<<<dim3(NR*4), blk256, 0, stream>>>(
        CONC, Wh+OFF_GO, 256, 256,  nullptr,nullptr,0,0,  nullptr,nullptr,0,0,
        go_b, nullptr, 0, GOUT, 256, 1, OP_NONE, 4);
    // 7. medium_out = MED2 * sigmoid([X,MED2]@fg^T + b) -> MOUT bf16
    gemm_k<<<dim3(NR*4), blk256, 0, stream>>>(
        Xh, Wh+OFF_FG, 512, 256,  MED2, Wh+OFF_FG+256, 512, 256,  nullptr,nullptr,0,0,
        fg_b, MED2, 1, MOUT, 256, 1, OP_SIGMUL, 4);
    // 8. pre_ln1 = X + [LH,MOUT,GOUT]@comb^T + b -> PRE1 fp32
    gemm_k<<<dim3(NR*4), blk256, 0, stream>>>(
        LH, Wh+OFF_COMB, 768, 256,  MOUT, Wh+OFF_COMB+256, 768, 256,  GOUT, Wh+OFF_COMB+512, 768, 256,
        comb_b, X, 0, PRE1, 256, 0, OP_ADDAUX, 4);
    // 9. pr = LN1 -> PR fp32 + PRh bf16
    ln_k<<<dim3(M_/4), blk256, 0, stream>>>(PRE1, ln1_g, ln1_b, PR, PRh);
    // 10. global_summary EMA -> GSUM bf16, final_traj -> out
    ema_p1h<<<scan_grid, blk256, 0, stream>>>(PRh, CAR0, 0.1f);
    ema_p3h<<<scan_grid, blk256, 0, stream>>>(PRh, CAR0, GSUM, 0.1f, out_tj);
    // 11. cs1 = pr + 0.3*(pr@p2s^T + b) -> CS1 bf16
    gemm_k<<<dim3(NR*4), blk256, 0, stream>>>(
        PRh, Wh+OFF_P2S, 256, 256,  nullptr,nullptr,0,0,  nullptr,nullptr,0,0,
        p2s_b, PR, 0, CS1, 256, 1, OP_AXPBY, 4);
    // 12. H1 = gelu(cs1@tr1a + gsum@tr1b + b) bf16
    gemm_k<<<dim3(NR*8), blk256, 0, stream>>>(
        CS1, Wh+OFF_TR1, 512, 256,  GSUM, Wh+OFF_TR1+256, 512, 256,  nullptr,nullptr,0,0,
        tr1_b, nullptr, 0, H1, 512, 1, OP_GELU, 8);
    // 13. scaled = 0.5*tanh(H1@tr2^T + b) -> SCALED fp32
    gemm_k<<<dim3(NR*4), blk256, 0, stream>>>(
        H1, Wh+OFF_TR2, 512, 512,  nullptr,nullptr,0,0,  nullptr,nullptr,0,0,
        tr2_b, nullptr, 0, SCALED, 256, 0, OP_TANHHALF, 4);
    // 14. state EMA + decayed initial -> PRE3 fp32
    ema_p1<<<scan_grid, blk256, 0, stream>>>(SCALED, CAR0, 1.0f);
    ema_p3_state<<<scan_grid, blk256, 0, stream>>>(SCALED, CAR0, SEQ, PRE3);
    // 15. states = LN3 -> STATESh bf16; final_state = LN4(states[-1]) -> out
    ln3_k<<<dim3(M_/4), blk256, 0, stream>>>(PRE3, ln3_g, ln3_b, STATESh, ln4_g, ln4_b, out_fs);
    // 16. ffn_in = pr + 0.3*(states@s2p^T + b) -> FFNIN bf16
    gemm_k<<<dim3(NR*4), blk256, 0, stream>>>(
        STATESh, Wh+OFF_S2P, 256, 256,  nullptr,nullptr,0,0,  nullptr,nullptr,0,0,
        s2p_b, PR, 0, FFNIN, 256, 1, OP_AXPBY, 4);
    // 17. H2 = gelu(ffn_in@ffn1^T + b) bf16
    gemm_k<<<dim3(NR*16), blk256, 0, stream>>>(
        FFNIN, Wh+OFF_FFN1, 256, 256,  nullptr,nullptr,0,0,  nullptr,nullptr,0,0,
        ffn1_b, nullptr, 0, H2, 1024, 1, OP_GELU, 16);
    // 18. pre_ln2 = pr + H2@ffn2^T + b -> PRE2 fp32
    gemm_k<<<dim3(NR*4), blk256, 0, stream>>>(
        H2, Wh+OFF_FFN2, 1024, 1024,  nullptr,nullptr,0,0,  nullptr,nullptr,0,0,
        ffn2_b, PR, 0, PRE2, 256, 0, OP_ADDAUX, 4);
    // 19. pr_out = LN2 -> d_out
    ln_k<<<dim3(M_/4), blk256, 0, stream>>>(PRE2, ln2_g, ln2_b, out_pr, nullptr);
}

// Round 8
// 283.635 us; speedup vs baseline: 1.7233x; 1.7233x over previous
//
#include <hip/hip_runtime.h>
#include <hip/hip_bf16.h>
#include <math.h>

#define D_  256
#define T_  2048
#define B_  4
#define M_  (B_*T_)
#define H_  4
#define HD_ 64

#define NC_ 64          // scan chunks
#define LCH (T_/NC_)    // 32 steps per chunk

enum { OP_NONE=0, OP_SIGMUL=1, OP_ADDAUX=2, OP_AXPBY=3, OP_GELU=4, OP_TANHHALF=5 };

typedef unsigned short u16;
typedef short short8 __attribute__((ext_vector_type(8)));
typedef float f32x4  __attribute__((ext_vector_type(4)));

__device__ __forceinline__ float gelu_f(float x){ return 0.5f*x*(1.0f+erff(x*0.70710678118654752f)); }
__device__ __forceinline__ float sigmoid_f(float x){ return 1.0f/(1.0f+expf(-x)); }

__device__ __forceinline__ unsigned pk2(float a, float b){
    __hip_bfloat162 h = __float22bfloat162_rn(make_float2(a,b));
    union { __hip_bfloat162 h; unsigned u; } c; c.h = h; return c.u;
}
__device__ __forceinline__ float bfu(u16 u){ return __uint_as_float(((unsigned)u)<<16); }
__device__ __forceinline__ u16 bf1(float x){ return (u16)(pk2(x,x)&0xffffu); }

// async global->LDS, 16B per lane; LDS dest is wave-uniform base + lane*16
__device__ __forceinline__ void gload16(const u16* g, u16* l){
    __builtin_amdgcn_global_load_lds(
        (const __attribute__((address_space(1))) unsigned int*)(const void*)g,
        (__attribute__((address_space(3))) unsigned int*)(void*)l,
        16, 0, 0);
}

// weight-pack element offsets inside Wh (u16 elements)
#define OFF_QKV   0u        // fused qkv(768)+gkv(512) rows -> [1280,256]
#define OFF_MO    327680u
#define OFF_FG    393216u
#define OFF_GO    524288u
#define OFF_COMB  589824u
#define OFF_FFN1  786432u
#define OFF_FFN2  1048576u
#define OFF_TR1   1310720u
#define OFF_TR2   1572864u
#define OFF_P2S   1703936u
#define OFF_S2P   1769472u
#define NWELEM    1835008u
#define NXELEM    2097152u

// ---------------------------------------------------------------------------
// One-shot fp32 -> bf16 conversion of all weights + X, and qkv/gkv bias concat.
// ---------------------------------------------------------------------------
__global__ __launch_bounds__(256) void cvt_k(
    const float* __restrict__ qkv_w, const float* __restrict__ gkv_w,
    const float* __restrict__ qkv_b, const float* __restrict__ gkv_b,
    const float* __restrict__ mo_w,  const float* __restrict__ fg_w,
    const float* __restrict__ go_w,  const float* __restrict__ comb_w,
    const float* __restrict__ ffn1_w,const float* __restrict__ ffn2_w,
    const float* __restrict__ tr1_w, const float* __restrict__ tr2_w,
    const float* __restrict__ p2s_w, const float* __restrict__ s2p_w,
    const float* __restrict__ X,
    u16* __restrict__ Wh, u16* __restrict__ Xh, float* __restrict__ bq)
{
    size_t i = ((size_t)blockIdx.x*256 + threadIdx.x)*4;
    if (i < NWELEM){
        const float* s; size_t base;
        if      (i < OFF_MO)  { s=(i<196608)?qkv_w:gkv_w; base=(i<196608)?0:196608; }
        else if (i < OFF_FG)  { s=mo_w;   base=OFF_MO; }
        else if (i < OFF_GO)  { s=fg_w;   base=OFF_FG; }
        else if (i < OFF_COMB){ s=go_w;   base=OFF_GO; }
        else if (i < OFF_FFN1){ s=comb_w; base=OFF_COMB; }
        else if (i < OFF_FFN2){ s=ffn1_w; base=OFF_FFN1; }
        else if (i < OFF_TR1) { s=ffn2_w; base=OFF_FFN2; }
        else if (i < OFF_TR2) { s=tr1_w;  base=OFF_TR1; }
        else if (i < OFF_P2S) { s=tr2_w;  base=OFF_TR2; }
        else if (i < OFF_S2P) { s=p2s_w;  base=OFF_P2S; }
        else                  { s=s2p_w;  base=OFF_S2P; }
        float4 v = *(const float4*)(s + (i-base));
        *(uint2*)(Wh + i) = (uint2){ pk2(v.x,v.y), pk2(v.z,v.w) };
    } else if (i < NWELEM + NXELEM){
        size_t j = i - NWELEM;
        float4 v = *(const float4*)(X + j);
        *(uint2*)(Xh + j) = (uint2){ pk2(v.x,v.y), pk2(v.z,v.w) };
    } else if (i < NWELEM + NXELEM + 1280){
        size_t j = i - (NWELEM + NXELEM);
        #pragma unroll
        for (int k=0;k<4;++k){
            size_t e = j + k;
            bq[e] = (e < 768) ? qkv_b[e] : gkv_b[e-768];
        }
    }
}

// ---------------------------------------------------------------------------
// bf16 MFMA GEMM: global_load_lds staging (no VGPR round-trip), BK=64,
// double-buffered LDS, one barrier per K-step. Tile 64x64, 4 waves (2x2).
// LDS swizzle realized by pre-swizzling the per-lane GLOBAL source chunk
// (lane&7)^(lane>>3); LDS dest stays linear; ds_read applies the same XOR.
// ---------------------------------------------------------------------------
__global__ __launch_bounds__(256) void gemm_k(
    const u16* __restrict__ A0, const u16* __restrict__ W0, int ldw0, int K0,
    const u16* __restrict__ A1, const u16* __restrict__ W1, int ldw1, int K1,
    const u16* __restrict__ A2, const u16* __restrict__ W2, int ldw2, int K2,
    const float* __restrict__ bias, const void* __restrict__ aux, int aux_bf16,
    void* __restrict__ C, int ldc, int c_bf16, int op, int ncol)
{
    __shared__ u16 As[2][64*64];
    __shared__ u16 Ws[2][64*64];

    const int q8   = gridDim.x >> 3;
    const int lid  = (blockIdx.x & 7)*q8 + (blockIdx.x >> 3);
    const int brow = lid / ncol;
    const int bcol = lid - brow*ncol;
    const int row0 = brow*64, col0 = bcol*64;

    const int tid  = threadIdx.x;
    const int lane = tid & 63, wid = tid >> 6;
    const int wm = (wid >> 1)*32, wn = (wid & 1)*32;
    const int l15 = lane & 15, l4 = lane >> 4;
    const int row8 = lane >> 3;               // 0..7 within a 1KB wave chunk
    const int sch  = ((lane & 7) ^ row8) * 8; // pre-swizzled source chunk

    f32x4 acc[2][2];
    #pragma unroll
    for (int i=0;i<2;++i)
        #pragma unroll
        for (int j=0;j<2;++j) acc[i][j] = (f32x4){0.f,0.f,0.f,0.f};

    auto issuetile = [&](const u16* A, const u16* W, int ldw, int K, int kb, int buf){
        #pragma unroll
        for (int iss=0; iss<2; ++iss){
            const int rowb = wid*16 + iss*8;   // wave-uniform
            gload16(A + (size_t)(row0+rowb+row8)*K   + kb + sch, &As[buf][rowb*64]);
            gload16(W + (size_t)(col0+rowb+row8)*ldw + kb + sch, &Ws[buf][rowb*64]);
        }
    };
    auto mfma_tile = [&](int buf){
        #pragma unroll
        for (int ks=0;ks<2;++ks){
            const int koff = ks*32 + l4*8;
            short8 af[2], bf[2];
            #pragma unroll
            for (int f=0;f<2;++f){
                const int ar = wm + f*16 + l15;
                af[f] = *(const short8*)&As[buf][(ar*64 + koff) ^ ((ar&7)<<3)];
                const int brn = wn + f*16 + l15;
                bf[f] = *(const short8*)&Ws[buf][(brn*64 + koff) ^ ((brn&7)<<3)];
            }
            #pragma unroll
            for (int fm=0;fm<2;++fm)
                #pragma unroll
                for (int fn=0;fn<2;++fn)
                    acc[fm][fn] = __builtin_amdgcn_mfma_f32_16x16x32_bf16(
                        af[fm], bf[fn], acc[fm][fn], 0, 0, 0);
        }
    };

    const u16* Ac = A0; const u16* Wc = W0; int ldwc = ldw0, Kc = K0, kb = 0, buf = 0;
    issuetile(Ac, Wc, ldwc, Kc, 0, 0);
    while (true){
        __syncthreads();            // vmcnt(0) drain: tile 'buf' DMA complete; all waves past prev MFMA
        int nkb = kb + 64;
        const u16* nA = Ac; const u16* nW = Wc; int nld = ldwc, nK = Kc;
        bool have_next = true;
        if (nkb >= Kc){
            if (Ac == A0 && A1){ nA = A1; nW = W1; nld = ldw1; nK = K1; nkb = 0; }
            else if (Ac == A1 && A2){ nA = A2; nW = W2; nld = ldw2; nK = K2; nkb = 0; }
            else have_next = false;
        }
        if (have_next) issuetile(nA, nW, nld, nK, nkb, buf^1);  // in flight across MFMA
        mfma_tile(buf);
        if (!have_next) break;
        Ac = nA; Wc = nW; ldwc = nld; Kc = nK; kb = nkb; buf ^= 1;
    }

    #pragma unroll
    for (int fn=0;fn<2;++fn){
        const int n = col0 + wn + fn*16 + l15;
        const float bv = bias[n];
        #pragma unroll
        for (int fm=0;fm<2;++fm){
            #pragma unroll
            for (int j=0;j<4;++j){
                const int m = row0 + wm + fm*16 + l4*4 + j;
                float v = acc[fm][fn][j] + bv;
                if (op==OP_GELU)          v = gelu_f(v);
                else if (op==OP_TANHHALF) v = 0.5f*tanhf(v);
                else if (op!=OP_NONE){
                    const size_t ai = (size_t)m*D_ + n;
                    const float a = aux_bf16 ? bfu(((const u16*)aux)[ai])
                                             : ((const float*)aux)[ai];
                    if (op==OP_SIGMUL)      v = a*sigmoid_f(v);
                    else if (op==OP_ADDAUX) v = v + a;
                    else                    v = a + 0.3f*v;
                }
                if (c_bf16) ((u16*)C)[(size_t)m*ldc + n] = bf1(v);
                else        ((float*)C)[(size_t)m*ldc + n] = v;
            }
        }
    }
}

// ---------------------------------------------------------------------------
// Depthwise causal conv, K=8, pad left 7. bf16 in, bf16 out.
// ---------------------------------------------------------------------------
__global__ __launch_bounds__(256) void conv_k(const u16* __restrict__ Xh,
    const float* __restrict__ w, const float* __restrict__ bias, u16* __restrict__ out)
{
    int idx = blockIdx.x*256 + threadIdx.x;
    int d = idx & (D_-1);
    int bt = idx >> 8;
    int t = bt & (T_-1);
    float acc = bias[d];
    const u16* xp = Xh + (size_t)bt*D_ + d;
    const float* wp = w + d*8;
    #pragma unroll
    for (int j=0;j<8;++j){
        int tt = t - 7 + j;
        if (tt >= 0) acc += bfu(xp[(size_t)(j-7)*D_]) * wp[j];
    }
    out[idx] = bf1(acc);
}

// ---------------------------------------------------------------------------
// MFMA banded attention. Per block: (b, h, 64-query tile), 4 waves.
// V transposed in-LDS from QKVG (no VT buffer).
// ---------------------------------------------------------------------------
__global__ __launch_bounds__(256) void attn_k(const u16* __restrict__ QKVG,
    u16* __restrict__ MED)
{
    __shared__ u16 Kl[128*64];
    __shared__ u16 Ql[64*64];
    __shared__ u16 Vl[64*128];
    const int b = blockIdx.z, h = blockIdx.y;
    const int t0 = blockIdx.x * 64;
    const int kb0 = t0 - 64;
    const int tid = threadIdx.x;

    {   // stage K (128 key rows x 64 dims), Q (64 rows), V transposed (64 d x 128 k)
        const int r0 = tid >> 3, c8 = (tid & 7) * 8;
        #pragma unroll
        for (int rep=0;rep<4;++rep){
            const int r = r0 + rep*32;
            const int kg = kb0 + r;
            uint4 pk = {0,0,0,0}, pv = {0,0,0,0};
            if (kg >= 0){
                const u16* gp = QKVG + ((size_t)(b*T_ + kg))*1280 + h*HD_ + c8;
                pk = *(const uint4*)(gp + 256);
                pv = *(const uint4*)(gp + 512);
            }
            *(uint4*)&Kl[(r*64 + c8) ^ ((r&7)<<3)] = pk;
            const u16* pvu = (const u16*)&pv;
            #pragma unroll
            for (int j=0;j<8;++j){
                const int d = c8 + j;
                Vl[(d*128 + r) ^ ((d&15)<<3)] = pvu[j];
            }
        }
        #pragma unroll
        for (int rep=0;rep<2;++rep){
            const int r = r0 + rep*32;
            uint4 pq = *(const uint4*)(QKVG + ((size_t)(b*T_ + t0 + r))*1280 + h*HD_ + c8);
            *(uint4*)&Ql[(r*64 + c8) ^ ((r&7)<<3)] = pq;
        }
    }
    __syncthreads();

    const int lane = tid & 63, w = tid >> 6;
    const int l15 = lane & 15, l4 = lane >> 4;

    short8 bq[2];
    {
        const int qr = w*16 + l15;
        bq[0] = *(const short8*)&Ql[(qr*64 +      l4*8) ^ ((qr&7)<<3)];
        bq[1] = *(const short8*)&Ql[(qr*64 + 32 + l4*8) ^ ((qr&7)<<3)];
    }

    f32x4 s[8];
    #pragma unroll
    for (int kf=0;kf<8;++kf){
        const int kr = kf*16 + l15;
        short8 a0 = *(const short8*)&Kl[(kr*64 +      l4*8) ^ ((kr&7)<<3)];
        short8 a1 = *(const short8*)&Kl[(kr*64 + 32 + l4*8) ^ ((kr&7)<<3)];
        f32x4 acc = (f32x4){0.f,0.f,0.f,0.f};
        acc = __builtin_amdgcn_mfma_f32_16x16x32_bf16(a0, bq[0], acc, 0,0,0);
        acc = __builtin_amdgcn_mfma_f32_16x16x32_bf16(a1, bq[1], acc, 0,0,0);
        s[kf] = acc;
    }

    const int qg = t0 + w*16 + l15;
    float m = -1e30f;
    #pragma unroll
    for (int kf=0;kf<8;++kf){
        #pragma unroll
        for (int j=0;j<4;++j){
            const int kg = kb0 + kf*16 + l4*4 + j;
            const int diff = qg - kg;
            const float v = (kg >= 0 && diff >= 0 && diff < 64) ? s[kf][j]*0.125f : -1e30f;
            s[kf][j] = v;
            m = fmaxf(m, v);
        }
    }
    m = fmaxf(m, __shfl_xor(m,16));
    m = fmaxf(m, __shfl_xor(m,32));
    float lsum = 0.f;
    unsigned lo[8], hi[8];
    #pragma unroll
    for (int kf=0;kf<8;++kf){
        const float p0 = expf(s[kf][0]-m), p1 = expf(s[kf][1]-m);
        const float p2 = expf(s[kf][2]-m), p3 = expf(s[kf][3]-m);
        lsum += (p0+p1)+(p2+p3);
        lo[kf] = pk2(p0,p1);
        hi[kf] = pk2(p2,p3);
    }
    lsum += __shfl_xor(lsum,16);
    lsum += __shfl_xor(lsum,32);
    const float inv = 1.f/lsum;

    f32x4 o[4];
    #pragma unroll
    for (int df=0;df<4;++df) o[df] = (f32x4){0.f,0.f,0.f,0.f};
    const int baseLane = l15 + ((l4&1)<<5);
    const bool hiHalf = (l4>>1) != 0;
    #pragma unroll
    for (int kb=0;kb<4;++kb){
        const int x0 = __shfl((int)lo[2*kb],   baseLane);
        const int x1 = __shfl((int)hi[2*kb],   baseLane);
        const int x2 = __shfl((int)lo[2*kb],   baseLane+16);
        const int x3 = __shfl((int)hi[2*kb],   baseLane+16);
        const int y0 = __shfl((int)lo[2*kb+1], baseLane);
        const int y1 = __shfl((int)hi[2*kb+1], baseLane);
        const int y2 = __shfl((int)lo[2*kb+1], baseLane+16);
        const int y3 = __shfl((int)hi[2*kb+1], baseLane+16);
        int4 afi;
        afi.x = hiHalf ? y0 : x0;
        afi.y = hiHalf ? y1 : x1;
        afi.z = hiHalf ? y2 : x2;
        afi.w = hiHalf ? y3 : x3;
        union { int4 i; short8 s; } cv; cv.i = afi;
        #pragma unroll
        for (int df=0;df<4;++df){
            const int vr = df*16 + l15;
            short8 bv = *(const short8*)&Vl[(vr*128 + kb*32 + l4*8) ^ ((vr&15)<<3)];
            o[df] = __builtin_amdgcn_mfma_f32_16x16x32_bf16(cv.s, bv, o[df], 0,0,0);
        }
    }

    #pragma unroll
    for (int j=0;j<4;++j){
        const float invj = __shfl(inv, l4*4 + j);
        const int mrow = b*T_ + t0 + w*16 + l4*4 + j;
        u16* op = MED + (size_t)mrow*D_ + h*HD_ + l15;
        #pragma unroll
        for (int df=0;df<4;++df)
            op[df*16] = bf1(o[df][j] * invj);
    }
}

// ---------------------------------------------------------------------------
// Chunked scans: p1 = per-chunk aggregate; p3 = own prefix + replay (no p2).
// ---------------------------------------------------------------------------
__global__ __launch_bounds__(256) void scan1_p1(const u16* __restrict__ QKVG,
    float* __restrict__ CA, float* __restrict__ CC)
{
    const int d = threadIdx.x, c = blockIdx.x, b = blockIdx.y;
    const u16* base = QKVG + ((size_t)(b*T_ + c*LCH))*1280;
    float sgk=0.f, sgkv=0.f;
    for (int t=0;t<LCH;++t){
        float gk = bfu(base[(size_t)t*1280 + 768 + d]);
        gk = gk > 0.f ? gk + 1.f : expf(gk);
        float gv = bfu(base[(size_t)t*1280 + 1024 + d]);
        sgk += gk; sgkv += gk*gv;
    }
    CA[((size_t)b*NC_ + c)*D_ + d] = sgk;
    CC[((size_t)b*NC_ + c)*D_ + d] = sgkv;
}

__global__ __launch_bounds__(256) void scan1_p3(const u16* __restrict__ QKVG,
    const float* __restrict__ CA, const float* __restrict__ CC, u16* __restrict__ CONC)
{
    const int d = threadIdx.x, c = blockIdx.x, b = blockIdx.y;
    float sgk = 0.f, sgkv = 0.f;
    for (int cc=0; cc<c; ++cc){
        sgk  += CA[((size_t)b*NC_ + cc)*D_ + d];
        sgkv += CC[((size_t)b*NC_ + cc)*D_ + d];
    }
    const u16* base = QKVG + ((size_t)(b*T_ + c*LCH))*1280;
    u16* out = CONC + ((size_t)(b*T_ + c*LCH))*D_ + d;
    for (int t=0;t<LCH;++t){
        float gk = bfu(base[(size_t)t*1280 + 768 + d]);
        gk = gk > 0.f ? gk + 1.f : expf(gk);
        float gv = bfu(base[(size_t)t*1280 + 1024 + d]);
        sgk += gk; sgkv += gk*gv;
        out[(size_t)t*D_] = bf1(sgkv / (sgk + 1e-5f));
    }
}

// EMA p1: bf16 input
__global__ __launch_bounds__(256) void ema_p1h(const u16* __restrict__ X,
    float* __restrict__ CARRY, float alpha)
{
    const int d = threadIdx.x, c = blockIdx.x, b = blockIdx.y;
    const u16* xp = X + ((size_t)(b*T_ + c*LCH))*D_ + d;
    float g = 0.f;
    for (int t=0;t<LCH;++t) g = 0.9f*g + alpha*bfu(xp[(size_t)t*D_]);
    CARRY[((size_t)b*NC_ + c)*D_ + d] = g;
}

// EMA p1: fp32 input
__global__ __launch_bounds__(256) void ema_p1(const float* __restrict__ X,
    float* __restrict__ CARRY, float alpha)
{
    const int d = threadIdx.x, c = blockIdx.x, b = blockIdx.y;
    const float* xp = X + ((size_t)(b*T_ + c*LCH))*D_ + d;
    float g = 0.f;
    for (int t=0;t<LCH;++t) g = 0.9f*g + alpha*xp[(size_t)t*D_];
    CARRY[((size_t)b*NC_ + c)*D_ + d] = g;
}

// EMA replay (bf16 in/out) + own prefix; last chunk writes traj.
__global__ __launch_bounds__(256) void ema_p3h(const u16* __restrict__ X,
    const float* __restrict__ CARRY, u16* __restrict__ OUT, float alpha,
    float* __restrict__ traj)
{
    const int d = threadIdx.x, c = blockIdx.x, b = blockIdx.y;
    const float dL = powf(0.9f, (float)LCH);
    float g = 0.f;
    for (int cc=0; cc<c; ++cc) g = CARRY[((size_t)b*NC_ + cc)*D_ + d] + dL*g;
    const u16* xp = X + ((size_t)(b*T_ + c*LCH))*D_ + d;
    u16* op = OUT + ((size_t)(b*T_ + c*LCH))*D_ + d;
    for (int t=0;t<LCH;++t){
        g = 0.9f*g + alpha*bfu(xp[(size_t)t*D_]);
        op[(size_t)t*D_] = bf1(g);
    }
    if (c == NC_-1) traj[b*D_ + d] = g;
}

// state EMA replay (fp32) + analytic initial decay, own prefix.
__global__ __launch_bounds__(256) void ema_p3_state(const float* __restrict__ X,
    const float* __restrict__ CARRY, const float* __restrict__ SEQ, float* __restrict__ OUT)
{
    const int d = threadIdx.x, c = blockIdx.x, b = blockIdx.y;
    const float dL = powf(0.9f, (float)LCH);
    float a = 0.f;
    for (int cc=0; cc<c; ++cc) a = CARRY[((size_t)b*NC_ + cc)*D_ + d] + dL*a;
    const float ss = SEQ[b*D_ + d];
    float dp = powf(0.9f, (float)(c*LCH + 1));
    const float* xp = X + ((size_t)(b*T_ + c*LCH))*D_ + d;
    float* op = OUT + ((size_t)(b*T_ + c*LCH))*D_ + d;
    for (int t=0;t<LCH;++t){
        a = 0.9f*a + xp[(size_t)t*D_];
        op[(size_t)t*D_] = fmaf(ss, dp, a);
        dp *= 0.9f;
    }
}

// ---------------------------------------------------------------------------
// LayerNorms
// ---------------------------------------------------------------------------
__global__ __launch_bounds__(256) void ln_k(const float* __restrict__ in,
    const float* __restrict__ g, const float* __restrict__ b,
    float* __restrict__ out, u16* __restrict__ out2)
{
    int row  = blockIdx.x*4 + (threadIdx.x>>6);
    int lane = threadIdx.x & 63;
    const float* ip = in + (size_t)row*D_ + lane*4;
    float4 x = *(const float4*)ip;
    float s  = x.x+x.y+x.z+x.w;
    float s2 = x.x*x.x + x.y*x.y + x.z*x.z + x.w*x.w;
    #pragma unroll
    for (int o=1;o<64;o<<=1){ s += __shfl_xor(s,o); s2 += __shfl_xor(s2,o); }
    float mean = s * (1.f/256.f);
    float var  = s2 * (1.f/256.f) - mean*mean;
    float rs = rsqrtf(var + 1e-5f);
    int db = lane*4;
    float4 r;
    r.x=(x.x-mean)*rs*g[db+0]+b[db+0];
    r.y=(x.y-mean)*rs*g[db+1]+b[db+1];
    r.z=(x.z-mean)*rs*g[db+2]+b[db+2];
    r.w=(x.w-mean)*rs*g[db+3]+b[db+3];
    *(float4*)(out + (size_t)row*D_ + db) = r;
    if (out2)
        *(uint2*)(out2 + (size_t)row*D_ + db) = (uint2){ pk2(r.x,r.y), pk2(r.z,r.w) };
}

__global__ __launch_bounds__(256) void ln3_k(const float* __restrict__ in,
    const float* __restrict__ g3, const float* __restrict__ b3, u16* __restrict__ states,
    const float* __restrict__ g4, const float* __restrict__ b4, float* __restrict__ fsout)
{
    int row  = blockIdx.x*4 + (threadIdx.x>>6);
    int lane = threadIdx.x & 63;
    const float* ip = in + (size_t)row*D_ + lane*4;
    float4 x = *(const float4*)ip;
    float s  = x.x+x.y+x.z+x.w;
    float s2 = x.x*x.x + x.y*x.y + x.z*x.z + x.w*x.w;
    #pragma unroll
    for (int o=1;o<64;o<<=1){ s += __shfl_xor(s,o); s2 += __shfl_xor(s2,o); }
    float mean = s * (1.f/256.f);
    float var  = s2 * (1.f/256.f) - mean*mean;
    float rs = rsqrtf(var + 1e-5f);
    int db = lane*4;
    float4 st;
    st.x=(x.x-mean)*rs*g3[db+0]+b3[db+0];
    st.y=(x.y-mean)*rs*g3[db+1]+b3[db+1];
    st.z=(x.z-mean)*rs*g3[db+2]+b3[db+2];
    st.w=(x.w-mean)*rs*g3[db+3]+b3[db+3];
    *(uint2*)(states + (size_t)row*D_ + db) = (uint2){ pk2(st.x,st.y), pk2(st.z,st.w) };

    if ((row & (T_-1)) == T_-1){
        float u  = st.x+st.y+st.z+st.w;
        float u2 = st.x*st.x + st.y*st.y + st.z*st.z + st.w*st.w;
        #pragma unroll
        for (int o=1;o<64;o<<=1){ u += __shfl_xor(u,o); u2 += __shfl_xor(u2,o); }
        float m2 = u * (1.f/256.f);
        float v2 = u2 * (1.f/256.f) - m2*m2;
        float r2 = rsqrtf(v2 + 1e-5f);
        float4 fs;
        fs.x=(st.x-m2)*r2*g4[db+0]+b4[db+0];
        fs.y=(st.y-m2)*r2*g4[db+1]+b4[db+1];
        fs.z=(st.z-m2)*r2*g4[db+2]+b4[db+2];
        fs.w=(st.w-m2)*r2*g4[db+3]+b4[db+3];
        *(float4*)(fsout + (size_t)(row>>11)*D_ + db) = fs;
    }
}

// ---------------------------------------------------------------------------
extern "C" void kernel_launch(void* const* d_in, const int* in_sizes, int n_in,
                              void* d_out, int out_size, void* d_ws, size_t ws_size,
                              hipStream_t stream)
{
    const float* X     = (const float*)d_in[0];
    const float* SEQ   = (const float*)d_in[1];
    const float* conv_w= (const float*)d_in[3];
    const float* conv_b= (const float*)d_in[4];
    const float* qkv_w = (const float*)d_in[5];
    const float* qkv_b = (const float*)d_in[6];
    const float* mo_w  = (const float*)d_in[7];
    const float* mo_b  = (const float*)d_in[8];
    const float* fg_w  = (const float*)d_in[9];
    const float* fg_b  = (const float*)d_in[10];
    const float* gkv_w = (const float*)d_in[11];
    const float* gkv_b = (const float*)d_in[12];
    const float* go_w  = (const float*)d_in[13];
    const float* go_b  = (const float*)d_in[14];
    const float* comb_w= (const float*)d_in[15];
    const float* comb_b= (const float*)d_in[16];
    const float* ffn1_w= (const float*)d_in[17];
    const float* ffn1_b= (const float*)d_in[18];
    const float* ffn2_w= (const float*)d_in[19];
    const float* ffn2_b= (const float*)d_in[20];
    const float* tr1_w = (const float*)d_in[21];
    const float* tr1_b = (const float*)d_in[22];
    const float* tr2_w = (const float*)d_in[23];
    const float* tr2_b = (const float*)d_in[24];
    const float* p2s_w = (const float*)d_in[25];
    const float* p2s_b = (const float*)d_in[26];
    const float* s2p_w = (const float*)d_in[27];
    const float* s2p_b = (const float*)d_in[28];
    const float* ln1_g = (const float*)d_in[29];
    const float* ln1_b = (const float*)d_in[30];
    const float* ln2_g = (const float*)d_in[31];
    const float* ln2_b = (const float*)d_in[32];
    const float* ln3_g = (const float*)d_in[33];
    const float* ln3_b = (const float*)d_in[34];
    const float* ln4_g = (const float*)d_in[35];
    const float* ln4_b = (const float*)d_in[36];

    // -------- workspace carve (256-byte aligned chunks) --------
    char* p = (char*)d_ws;
    auto alloc = [&](size_t bytes)->char*{ char* r = p; p += (bytes + 255) & ~(size_t)255; return r; };

    u16*   QKVG = (u16*)  alloc((size_t)M_*1280*2);
    u16*   Wh   = (u16*)  alloc((size_t)NWELEM*2);
    float* bq   = (float*)alloc(1280*4);
    u16*   Xh   = (u16*)  alloc((size_t)M_*256*2);
    u16*   MED  = (u16*)  alloc((size_t)M_*256*2);
    u16*   MED2 = (u16*)  alloc((size_t)M_*256*2);
    u16*   LH   = (u16*)  alloc((size_t)M_*256*2);
    u16*   CONC = (u16*)  alloc((size_t)M_*256*2);
    u16*   GOUT = (u16*)  alloc((size_t)M_*256*2);
    u16*   MOUT = (u16*)  alloc((size_t)M_*256*2);
    float* PRE1 = (float*)alloc((size_t)M_*256*4);
    float* PR   = (float*)alloc((size_t)M_*256*4);
    u16*   PRh  = (u16*)  alloc((size_t)M_*256*2);
    u16*   GSUM = (u16*)  alloc((size_t)M_*256*2);
    u16*   CS1  = (u16*)  alloc((size_t)M_*256*2);
    u16*   H1   = (u16*)  alloc((size_t)M_*512*2);
    float* SCALED=(float*)alloc((size_t)M_*256*4);
    float* PRE3 = (float*)alloc((size_t)M_*256*4);
    u16*   STATESh=(u16*) alloc((size_t)M_*256*2);
    u16*   FFNIN= (u16*)  alloc((size_t)M_*256*2);
    u16*   H2   = (u16*)  alloc((size_t)M_*1024*2);
    float* PRE2 = (float*)alloc((size_t)M_*256*4);
    float* CAR0 = (float*)alloc((size_t)B_*NC_*D_*4);
    float* CAR1 = (float*)alloc((size_t)B_*NC_*D_*4);

    float* out_pr = (float*)d_out;
    float* out_fs = out_pr + (size_t)M_*256;
    float* out_tj = out_fs + B_*256;

    const dim3 blk256(256);
    const dim3 scan_grid(NC_, B_);
    const int NR = M_/64;   // 128 row tiles

    // 0. convert weights + X to bf16, concat qkv/gkv bias
    cvt_k<<<dim3(3842), blk256, 0, stream>>>(
        qkv_w, gkv_w, qkv_b, gkv_b, mo_w, fg_w, go_w, comb_w,
        ffn1_w, ffn2_w, tr1_w, tr2_w, p2s_w, s2p_w, X, Wh, Xh, bq);
    // 1. fused qkv+gkv projection -> QKVG (bf16)
    gemm_k<<<dim3(NR*20), blk256, 0, stream>>>(
        Xh, Wh+OFF_QKV, 256, 256,  nullptr,nullptr,0,0,  nullptr,nullptr,0,0,
        bq, nullptr, 0, QKVG, 1280, 1, OP_NONE, 20);
    // 2. local_history (depthwise conv) -> LH bf16
    conv_k<<<dim3(M_*D_/256), blk256, 0, stream>>>(Xh, conv_w, conv_b, LH);
    // 3. banded attention (MFMA, V transposed in-LDS) -> MED bf16
    attn_k<<<dim3(T_/64, H_, B_), blk256, 0, stream>>>(QKVG, MED);
    // 4. mo projection -> MED2 bf16
    gemm_k<<<dim3(NR*4), blk256, 0, stream>>>(
        MED, Wh+OFF_MO, 256, 256,  nullptr,nullptr,0,0,  nullptr,nullptr,0,0,
        mo_b, nullptr, 0, MED2, 256, 1, OP_NONE, 4);
    // 5. concepts scan -> CONC bf16
    scan1_p1<<<scan_grid, blk256, 0, stream>>>(QKVG, CAR0, CAR1);
    scan1_p3<<<scan_grid, blk256, 0, stream>>>(QKVG, CAR0, CAR1, CONC);
    // 6. global_out -> GOUT bf16
    gemm_k<<<dim3(NR*4), blk256, 0, stream>>>(
        CONC, Wh+OFF_GO, 256, 256,  nullptr,nullptr,0,0,  nullptr,nullptr,0,0,
        go_b, nullptr, 0, GOUT, 256, 1, OP_NONE, 4);
    // 7. medium_out = MED2 * sigmoid([X,MED2]@fg^T + b) -> MOUT bf16
    gemm_k<<<dim3(NR*4), blk256, 0, stream>>>(
        Xh, Wh+OFF_FG, 512, 256,  MED2, Wh+OFF_FG+256, 512, 256,  nullptr,nullptr,0,0,
        fg_b, MED2, 1, MOUT, 256, 1, OP_SIGMUL, 4);
    // 8. pre_ln1 = X + [LH,MOUT,GOUT]@comb^T + b -> PRE1 fp32
    gemm_k<<<dim3(NR*4), blk256, 0, stream>>>(
        LH, Wh+OFF_COMB, 768, 256,  MOUT, Wh+OFF_COMB+256, 768, 256,  GOUT, Wh+OFF_COMB+512, 768, 256,
        comb_b, X, 0, PRE1, 256, 0, OP_ADDAUX, 4);
    // 9. pr = LN1 -> PR fp32 + PRh bf16
    ln_k<<<dim3(M_/4), blk256, 0, stream>>>(PRE1, ln1_g, ln1_b, PR, PRh);
    // 10. global_summary EMA -> GSUM bf16, final_traj -> out
    ema_p1h<<<scan_grid, blk256, 0, stream>>>(PRh, CAR0, 0.1f);
    ema_p3h<<<scan_grid, blk256, 0, stream>>>(PRh, CAR0, GSUM, 0.1f, out_tj);
    // 11. cs1 = pr + 0.3*(pr@p2s^T + b) -> CS1 bf16
    gemm_k<<<dim3(NR*4), blk256, 0, stream>>>(
        PRh, Wh+OFF_P2S, 256, 256,  nullptr,nullptr,0,0,  nullptr,nullptr,0,0,
        p2s_b, PR, 0, CS1, 256, 1, OP_AXPBY, 4);
    // 12. H1 = gelu(cs1@tr1a + gsum@tr1b + b) bf16
    gemm_k<<<dim3(NR*8), blk256, 0, stream>>>(
        CS1, Wh+OFF_TR1, 512, 256,  GSUM, Wh+OFF_TR1+256, 512, 256,  nullptr,nullptr,0,0,
        tr1_b, nullptr, 0, H1, 512, 1, OP_GELU, 8);
    // 13. scaled = 0.5*tanh(H1@tr2^T + b) -> SCALED fp32
    gemm_k<<<dim3(NR*4), blk256, 0, stream>>>(
        H1, Wh+OFF_TR2, 512, 512,  nullptr,nullptr,0,0,  nullptr,nullptr,0,0,
        tr2_b, nullptr, 0, SCALED, 256, 0, OP_TANHHALF, 4);
    // 14. state EMA + decayed initial -> PRE3 fp32
    ema_p1<<<scan_grid, blk256, 0, stream>>>(SCALED, CAR0, 1.0f);
    ema_p3_state<<<scan_grid, blk256, 0, stream>>>(SCALED, CAR0, SEQ, PRE3);
    // 15. states = LN3 -> STATESh bf16; final_state = LN4(states[-1]) -> out
    ln3_k<<<dim3(M_/4), blk256, 0, stream>>>(PRE3, ln3_g, ln3_b, STATESh, ln4_g, ln4_b, out_fs);
    // 16. ffn_in = pr + 0.3*(states@s2p^T + b) -> FFNIN bf16
    gemm_k<<<dim3(NR*4), blk256, 0, stream>>>(
        STATESh, Wh+OFF_S2P, 256, 256,  nullptr,nullptr,0,0,  nullptr,nullptr,0,0,
        s2p_b, PR, 0, FFNIN, 256, 1, OP_AXPBY, 4);
    // 17. H2 = gelu(ffn_in@ffn1^T + b) bf16
    gemm_k<<<dim3(NR*16), blk256, 0, stream>>>(
        FFNIN, Wh+OFF_FFN1, 256, 256,  nullptr,nullptr,0,0,  nullptr,nullptr,0,0,
        ffn1_b, nullptr, 0, H2, 1024, 1, OP_GELU, 16);
    // 18. pre_ln2 = pr + H2@ffn2^T + b -> PRE2 fp32
    gemm_k<<<dim3(NR*4), blk256, 0, stream>>>(
        H2, Wh+OFF_FFN2, 1024, 1024,  nullptr,nullptr,0,0,  nullptr,nullptr,0,0,
        ffn2_b, PR, 0, PRE2, 256, 0, OP_ADDAUX, 4);
    // 19. pr_out = LN2 -> d_out
    ln_k<<<dim3(M_/4), blk256, 0, stream>>>(PRE2, ln2_g, ln2_b, out_pr, nullptr);
}

// Round 9
// 259.789 us; speedup vs baseline: 1.8815x; 1.0918x over previous
//
#include <hip/hip_runtime.h>
#include <hip/hip_bf16.h>
#include <math.h>

#define D_  256
#define T_  2048
#define B_  4
#define M_  (B_*T_)
#define H_  4
#define HD_ 64

#define NC_ 64          // scan chunks
#define LCH (T_/NC_)    // 32 steps per chunk

enum { OP_NONE=0, OP_SIGMUL=1, OP_ADDAUX=2, OP_AXPBY=3, OP_GELU=4, OP_TANHHALF=5 };

typedef unsigned short u16;
typedef short short8 __attribute__((ext_vector_type(8)));
typedef float f32x4  __attribute__((ext_vector_type(4)));

__device__ __forceinline__ float gelu_f(float x){ return 0.5f*x*(1.0f+erff(x*0.70710678118654752f)); }
__device__ __forceinline__ float sigmoid_f(float x){ return 1.0f/(1.0f+expf(-x)); }

__device__ __forceinline__ unsigned pk2(float a, float b){
    __hip_bfloat162 h = __float22bfloat162_rn(make_float2(a,b));
    union { __hip_bfloat162 h; unsigned u; } c; c.h = h; return c.u;
}
__device__ __forceinline__ float bfu(u16 u){ return __uint_as_float(((unsigned)u)<<16); }
__device__ __forceinline__ u16 bf1(float x){ return (u16)(pk2(x,x)&0xffffu); }

// weight-pack element offsets inside Wh (u16 elements)
#define OFF_QKV   0u        // fused qkv(768)+gkv(512) rows -> [1280,256]
#define OFF_MO    327680u
#define OFF_FG    393216u
#define OFF_GO    524288u
#define OFF_COMB  589824u
#define OFF_FFN1  786432u
#define OFF_FFN2  1048576u
#define OFF_TR1   1310720u
#define OFF_TR2   1572864u
#define OFF_P2S   1703936u
#define OFF_S2P   1769472u
#define NWELEM    1835008u
#define NXELEM    2097152u

// ---------------------------------------------------------------------------
// One-shot fp32 -> bf16 conversion of all weights + X, and qkv/gkv bias concat.
// ---------------------------------------------------------------------------
__global__ __launch_bounds__(256) void cvt_k(
    const float* __restrict__ qkv_w, const float* __restrict__ gkv_w,
    const float* __restrict__ qkv_b, const float* __restrict__ gkv_b,
    const float* __restrict__ mo_w,  const float* __restrict__ fg_w,
    const float* __restrict__ go_w,  const float* __restrict__ comb_w,
    const float* __restrict__ ffn1_w,const float* __restrict__ ffn2_w,
    const float* __restrict__ tr1_w, const float* __restrict__ tr2_w,
    const float* __restrict__ p2s_w, const float* __restrict__ s2p_w,
    const float* __restrict__ X,
    u16* __restrict__ Wh, u16* __restrict__ Xh, float* __restrict__ bq)
{
    size_t i = ((size_t)blockIdx.x*256 + threadIdx.x)*4;
    if (i < NWELEM){
        const float* s; size_t base;
        if      (i < OFF_MO)  { s=(i<196608)?qkv_w:gkv_w; base=(i<196608)?0:196608; }
        else if (i < OFF_FG)  { s=mo_w;   base=OFF_MO; }
        else if (i < OFF_GO)  { s=fg_w;   base=OFF_FG; }
        else if (i < OFF_COMB){ s=go_w;   base=OFF_GO; }
        else if (i < OFF_FFN1){ s=comb_w; base=OFF_COMB; }
        else if (i < OFF_FFN2){ s=ffn1_w; base=OFF_FFN1; }
        else if (i < OFF_TR1) { s=ffn2_w; base=OFF_FFN2; }
        else if (i < OFF_TR2) { s=tr1_w;  base=OFF_TR1; }
        else if (i < OFF_P2S) { s=tr2_w;  base=OFF_TR2; }
        else if (i < OFF_S2P) { s=p2s_w;  base=OFF_P2S; }
        else                  { s=s2p_w;  base=OFF_S2P; }
        float4 v = *(const float4*)(s + (i-base));
        *(uint2*)(Wh + i) = (uint2){ pk2(v.x,v.y), pk2(v.z,v.w) };
    } else if (i < NWELEM + NXELEM){
        size_t j = i - NWELEM;
        float4 v = *(const float4*)(X + j);
        *(uint2*)(Xh + j) = (uint2){ pk2(v.x,v.y), pk2(v.z,v.w) };
    } else if (i < NWELEM + NXELEM + 1280){
        size_t j = i - (NWELEM + NXELEM);
        #pragma unroll
        for (int k=0;k<4;++k){
            size_t e = j + k;
            bq[e] = (e < 768) ? qkv_b[e] : gkv_b[e-768];
        }
    }
}

// ---------------------------------------------------------------------------
// bf16 MFMA GEMM, register-staged pipeline (r6 structure), tile 128x64, BK=64,
// 512 threads = 8 waves (4M x 2N), mfma_f32_16x16x32_bf16, XCD swizzle.
// Per-thread staging: A 2x uint4, W 1x uint4 (same envelope as r6 - no spill).
// ---------------------------------------------------------------------------
__global__ __launch_bounds__(512) void gemm_k(
    const u16* __restrict__ A0, const u16* __restrict__ W0, int ldw0, int K0,
    const u16* __restrict__ A1, const u16* __restrict__ W1, int ldw1, int K1,
    const u16* __restrict__ A2, const u16* __restrict__ W2, int ldw2, int K2,
    const float* __restrict__ bias, const void* __restrict__ aux, int aux_bf16,
    void* __restrict__ C, int ldc, int c_bf16, int op, int ncol)
{
    __shared__ u16 As[128*64];
    __shared__ u16 Ws[64*64];

    const int q8   = gridDim.x >> 3;
    const int lid  = (blockIdx.x & 7)*q8 + (blockIdx.x >> 3);
    const int brow = lid / ncol;
    const int bcol = lid - brow*ncol;
    const int row0 = brow*128, col0 = bcol*64;

    const int tid  = threadIdx.x;
    const int lane = tid & 63, wid = tid >> 6;        // 8 waves
    const int wm = (wid >> 1)*32, wn = (wid & 1)*32;  // wave tile 32x32
    const int l15 = lane & 15, l4 = lane >> 4;
    const int rowA = tid >> 2;            // 0..127
    const int scA  = (tid & 3) * 8;       // chunks 0..3 (and +32)
    const int rowW = tid >> 3;            // 0..63
    const int scW  = (tid & 7) * 8;

    f32x4 acc[2][2];
    #pragma unroll
    for (int i=0;i<2;++i)
        #pragma unroll
        for (int j=0;j<2;++j) acc[i][j] = (f32x4){0.f,0.f,0.f,0.f};

    uint4 ra0, ra1, rw0;

    auto loadtile = [&](const u16* A, const u16* W, int ldw, int K, int kb){
        const u16* ga = A + (size_t)(row0+rowA)*K + kb + scA;
        ra0 = *(const uint4*)ga;
        ra1 = *(const uint4*)(ga + 32);
        rw0 = *(const uint4*)(W + (size_t)(col0+rowW)*ldw + kb + scW);
    };
    auto storetile = [&](){
        const int sw = (rowA&7)<<3;
        *(uint4*)&As[(rowA*64 + scA) ^ sw]      = ra0;
        *(uint4*)&As[(rowA*64 + scA + 32) ^ sw] = ra1;
        *(uint4*)&Ws[(rowW*64 + scW) ^ ((rowW&7)<<3)] = rw0;
    };
    auto mfma_tile = [&](){
        #pragma unroll
        for (int ks=0;ks<2;++ks){
            const int koff = ks*32 + l4*8;
            short8 af[2], bf[2];
            #pragma unroll
            for (int f=0;f<2;++f){
                const int ar = wm + f*16 + l15;
                af[f] = *(const short8*)&As[(ar*64 + koff) ^ ((ar&7)<<3)];
                const int brn = wn + f*16 + l15;
                bf[f] = *(const short8*)&Ws[(brn*64 + koff) ^ ((brn&7)<<3)];
            }
            #pragma unroll
            for (int fm=0;fm<2;++fm)
                #pragma unroll
                for (int fn=0;fn<2;++fn)
                    acc[fm][fn] = __builtin_amdgcn_mfma_f32_16x16x32_bf16(
                        af[fm], bf[fn], acc[fm][fn], 0, 0, 0);
        }
    };

    const u16* Ac = A0; const u16* Wc = W0; int ldwc = ldw0, Kc = K0, kb = 0;
    loadtile(Ac, Wc, ldwc, Kc, 0);
    while (true){
        __syncthreads();            // prev MFMA done; LDS free
        storetile();
        __syncthreads();            // staged tile visible
        int nkb = kb + 64;
        const u16* nA = Ac; const u16* nW = Wc; int nld = ldwc, nK = Kc;
        bool have_next = true;
        if (nkb >= Kc){
            if (Ac == A0 && A1){ nA = A1; nW = W1; nld = ldw1; nK = K1; nkb = 0; }
            else if (Ac == A1 && A2){ nA = A2; nW = W2; nld = ldw2; nK = K2; nkb = 0; }
            else have_next = false;
        }
        if (have_next) loadtile(nA, nW, nld, nK, nkb);   // in flight across MFMA
        mfma_tile();
        if (!have_next) break;
        Ac = nA; Wc = nW; ldwc = nld; Kc = nK; kb = nkb;
    }

    #pragma unroll
    for (int fn=0;fn<2;++fn){
        const int n = col0 + wn + fn*16 + l15;
        const float bv = bias[n];
        #pragma unroll
        for (int fm=0;fm<2;++fm){
            #pragma unroll
            for (int j=0;j<4;++j){
                const int m = row0 + wm + fm*16 + l4*4 + j;
                float v = acc[fm][fn][j] + bv;
                if (op==OP_GELU)          v = gelu_f(v);
                else if (op==OP_TANHHALF) v = 0.5f*tanhf(v);
                else if (op!=OP_NONE){
                    const size_t ai = (size_t)m*D_ + n;
                    const float a = aux_bf16 ? bfu(((const u16*)aux)[ai])
                                             : ((const float*)aux)[ai];
                    if (op==OP_SIGMUL)      v = a*sigmoid_f(v);
                    else if (op==OP_ADDAUX) v = v + a;
                    else                    v = a + 0.3f*v;
                }
                if (c_bf16) ((u16*)C)[(size_t)m*ldc + n] = bf1(v);
                else        ((float*)C)[(size_t)m*ldc + n] = v;
            }
        }
    }
}

// ---------------------------------------------------------------------------
// Depthwise causal conv, K=8, pad left 7. bf16 in/out, 4 d's per thread.
// ---------------------------------------------------------------------------
__global__ __launch_bounds__(256) void conv_k(const u16* __restrict__ Xh,
    const float* __restrict__ w, const float* __restrict__ bias, u16* __restrict__ out)
{
    int idx = blockIdx.x*256 + threadIdx.x;       // over M*D/4
    int d4 = (idx & 63) * 4;
    int bt = idx >> 6;
    int t = bt & (T_-1);
    float a0 = bias[d4], a1 = bias[d4+1], a2 = bias[d4+2], a3 = bias[d4+3];
    const u16* xp = Xh + (size_t)bt*D_ + d4;
    #pragma unroll
    for (int j=0;j<8;++j){
        int tt = t - 7 + j;
        if (tt >= 0){
            uint2 v = *(const uint2*)(xp + (size_t)(j-7)*D_);
            a0 += bfu((u16)(v.x & 0xffff))      * w[(d4+0)*8 + j];
            a1 += bfu((u16)(v.x >> 16))         * w[(d4+1)*8 + j];
            a2 += bfu((u16)(v.y & 0xffff))      * w[(d4+2)*8 + j];
            a3 += bfu((u16)(v.y >> 16))         * w[(d4+3)*8 + j];
        }
    }
    *(uint2*)(out + (size_t)bt*D_ + d4) = (uint2){ pk2(a0,a1), pk2(a2,a3) };
}

// ---------------------------------------------------------------------------
// MFMA banded attention. Per block: (b, h, 64-query tile), 4 waves.
// V transposed in-LDS from QKVG.
// ---------------------------------------------------------------------------
__global__ __launch_bounds__(256) void attn_k(const u16* __restrict__ QKVG,
    u16* __restrict__ MED)
{
    __shared__ u16 Kl[128*64];
    __shared__ u16 Ql[64*64];
    __shared__ u16 Vl[64*128];
    const int b = blockIdx.z, h = blockIdx.y;
    const int t0 = blockIdx.x * 64;
    const int kb0 = t0 - 64;
    const int tid = threadIdx.x;

    {   // stage K (128 key rows x 64 dims), Q (64 rows), V transposed (64 d x 128 k)
        const int r0 = tid >> 3, c8 = (tid & 7) * 8;
        #pragma unroll
        for (int rep=0;rep<4;++rep){
            const int r = r0 + rep*32;
            const int kg = kb0 + r;
            uint4 pk = {0,0,0,0}, pv = {0,0,0,0};
            if (kg >= 0){
                const u16* gp = QKVG + ((size_t)(b*T_ + kg))*1280 + h*HD_ + c8;
                pk = *(const uint4*)(gp + 256);
                pv = *(const uint4*)(gp + 512);
            }
            *(uint4*)&Kl[(r*64 + c8) ^ ((r&7)<<3)] = pk;
            const u16* pvu = (const u16*)&pv;
            #pragma unroll
            for (int j=0;j<8;++j){
                const int d = c8 + j;
                Vl[(d*128 + r) ^ ((d&15)<<3)] = pvu[j];
            }
        }
        #pragma unroll
        for (int rep=0;rep<2;++rep){
            const int r = r0 + rep*32;
            uint4 pq = *(const uint4*)(QKVG + ((size_t)(b*T_ + t0 + r))*1280 + h*HD_ + c8);
            *(uint4*)&Ql[(r*64 + c8) ^ ((r&7)<<3)] = pq;
        }
    }
    __syncthreads();

    const int lane = tid & 63, w = tid >> 6;
    const int l15 = lane & 15, l4 = lane >> 4;

    short8 bq[2];
    {
        const int qr = w*16 + l15;
        bq[0] = *(const short8*)&Ql[(qr*64 +      l4*8) ^ ((qr&7)<<3)];
        bq[1] = *(const short8*)&Ql[(qr*64 + 32 + l4*8) ^ ((qr&7)<<3)];
    }

    f32x4 s[8];
    #pragma unroll
    for (int kf=0;kf<8;++kf){
        const int kr = kf*16 + l15;
        short8 a0 = *(const short8*)&Kl[(kr*64 +      l4*8) ^ ((kr&7)<<3)];
        short8 a1 = *(const short8*)&Kl[(kr*64 + 32 + l4*8) ^ ((kr&7)<<3)];
        f32x4 acc = (f32x4){0.f,0.f,0.f,0.f};
        acc = __builtin_amdgcn_mfma_f32_16x16x32_bf16(a0, bq[0], acc, 0,0,0);
        acc = __builtin_amdgcn_mfma_f32_16x16x32_bf16(a1, bq[1], acc, 0,0,0);
        s[kf] = acc;
    }

    const int qg = t0 + w*16 + l15;
    float m = -1e30f;
    #pragma unroll
    for (int kf=0;kf<8;++kf){
        #pragma unroll
        for (int j=0;j<4;++j){
            const int kg = kb0 + kf*16 + l4*4 + j;
            const int diff = qg - kg;
            const float v = (kg >= 0 && diff >= 0 && diff < 64) ? s[kf][j]*0.125f : -1e30f;
            s[kf][j] = v;
            m = fmaxf(m, v);
        }
    }
    m = fmaxf(m, __shfl_xor(m,16));
    m = fmaxf(m, __shfl_xor(m,32));
    float lsum = 0.f;
    unsigned lo[8], hi[8];
    #pragma unroll
    for (int kf=0;kf<8;++kf){
        const float p0 = expf(s[kf][0]-m), p1 = expf(s[kf][1]-m);
        const float p2 = expf(s[kf][2]-m), p3 = expf(s[kf][3]-m);
        lsum += (p0+p1)+(p2+p3);
        lo[kf] = pk2(p0,p1);
        hi[kf] = pk2(p2,p3);
    }
    lsum += __shfl_xor(lsum,16);
    lsum += __shfl_xor(lsum,32);
    const float inv = 1.f/lsum;

    f32x4 o[4];
    #pragma unroll
    for (int df=0;df<4;++df) o[df] = (f32x4){0.f,0.f,0.f,0.f};
    const int baseLane = l15 + ((l4&1)<<5);
    const bool hiHalf = (l4>>1) != 0;
    #pragma unroll
    for (int kb=0;kb<4;++kb){
        const int x0 = __shfl((int)lo[2*kb],   baseLane);
        const int x1 = __shfl((int)hi[2*kb],   baseLane);
        const int x2 = __shfl((int)lo[2*kb],   baseLane+16);
        const int x3 = __shfl((int)hi[2*kb],   baseLane+16);
        const int y0 = __shfl((int)lo[2*kb+1], baseLane);
        const int y1 = __shfl((int)hi[2*kb+1], baseLane);
        const int y2 = __shfl((int)lo[2*kb+1], baseLane+16);
        const int y3 = __shfl((int)hi[2*kb+1], baseLane+16);
        int4 afi;
        afi.x = hiHalf ? y0 : x0;
        afi.y = hiHalf ? y1 : x1;
        afi.z = hiHalf ? y2 : x2;
        afi.w = hiHalf ? y3 : x3;
        union { int4 i; short8 s; } cv; cv.i = afi;
        #pragma unroll
        for (int df=0;df<4;++df){
            const int vr = df*16 + l15;
            short8 bv = *(const short8*)&Vl[(vr*128 + kb*32 + l4*8) ^ ((vr&15)<<3)];
            o[df] = __builtin_amdgcn_mfma_f32_16x16x32_bf16(cv.s, bv, o[df], 0,0,0);
        }
    }

    #pragma unroll
    for (int j=0;j<4;++j){
        const float invj = __shfl(inv, l4*4 + j);
        const int mrow = b*T_ + t0 + w*16 + l4*4 + j;
        u16* op = MED + (size_t)mrow*D_ + h*HD_ + l15;
        #pragma unroll
        for (int df=0;df<4;++df)
            op[df*16] = bf1(o[df][j] * invj);
    }
}

// ---------------------------------------------------------------------------
// Chunked scans: p1 = per-chunk aggregate; p3 = own prefix + replay.
// ---------------------------------------------------------------------------
__global__ __launch_bounds__(256) void scan1_p1(const u16* __restrict__ QKVG,
    float* __restrict__ CA, float* __restrict__ CC)
{
    const int d = threadIdx.x, c = blockIdx.x, b = blockIdx.y;
    const u16* base = QKVG + ((size_t)(b*T_ + c*LCH))*1280;
    float sgk=0.f, sgkv=0.f;
    for (int t=0;t<LCH;++t){
        float gk = bfu(base[(size_t)t*1280 + 768 + d]);
        gk = gk > 0.f ? gk + 1.f : expf(gk);
        float gv = bfu(base[(size_t)t*1280 + 1024 + d]);
        sgk += gk; sgkv += gk*gv;
    }
    CA[((size_t)b*NC_ + c)*D_ + d] = sgk;
    CC[((size_t)b*NC_ + c)*D_ + d] = sgkv;
}

__global__ __launch_bounds__(256) void scan1_p3(const u16* __restrict__ QKVG,
    const float* __restrict__ CA, const float* __restrict__ CC, u16* __restrict__ CONC)
{
    const int d = threadIdx.x, c = blockIdx.x, b = blockIdx.y;
    float sgk = 0.f, sgkv = 0.f;
    for (int cc=0; cc<c; ++cc){
        sgk  += CA[((size_t)b*NC_ + cc)*D_ + d];
        sgkv += CC[((size_t)b*NC_ + cc)*D_ + d];
    }
    const u16* base = QKVG + ((size_t)(b*T_ + c*LCH))*1280;
    u16* out = CONC + ((size_t)(b*T_ + c*LCH))*D_ + d;
    for (int t=0;t<LCH;++t){
        float gk = bfu(base[(size_t)t*1280 + 768 + d]);
        gk = gk > 0.f ? gk + 1.f : expf(gk);
        float gv = bfu(base[(size_t)t*1280 + 1024 + d]);
        sgk += gk; sgkv += gk*gv;
        out[(size_t)t*D_] = bf1(sgkv / (sgk + 1e-5f));
    }
}

// EMA p1: bf16 input
__global__ __launch_bounds__(256) void ema_p1h(const u16* __restrict__ X,
    float* __restrict__ CARRY, float alpha)
{
    const int d = threadIdx.x, c = blockIdx.x, b = blockIdx.y;
    const u16* xp = X + ((size_t)(b*T_ + c*LCH))*D_ + d;
    float g = 0.f;
    for (int t=0;t<LCH;++t) g = 0.9f*g + alpha*bfu(xp[(size_t)t*D_]);
    CARRY[((size_t)b*NC_ + c)*D_ + d] = g;
}

// EMA replay (bf16 in/out) + own prefix; last chunk writes traj.
__global__ __launch_bounds__(256) void ema_p3h(const u16* __restrict__ X,
    const float* __restrict__ CARRY, u16* __restrict__ OUT, float alpha,
    float* __restrict__ traj)
{
    const int d = threadIdx.x, c = blockIdx.x, b = blockIdx.y;
    const float dL = powf(0.9f, (float)LCH);
    float g = 0.f;
    for (int cc=0; cc<c; ++cc) g = CARRY[((size_t)b*NC_ + cc)*D_ + d] + dL*g;
    const u16* xp = X + ((size_t)(b*T_ + c*LCH))*D_ + d;
    u16* op = OUT + ((size_t)(b*T_ + c*LCH))*D_ + d;
    for (int t=0;t<LCH;++t){
        g = 0.9f*g + alpha*bfu(xp[(size_t)t*D_]);
        op[(size_t)t*D_] = bf1(g);
    }
    if (c == NC_-1) traj[b*D_ + d] = g;
}

// state EMA replay (bf16 input) + analytic initial decay, own prefix; fp32 out.
__global__ __launch_bounds__(256) void ema_p3_state_h(const u16* __restrict__ X,
    const float* __restrict__ CARRY, const float* __restrict__ SEQ, float* __restrict__ OUT)
{
    const int d = threadIdx.x, c = blockIdx.x, b = blockIdx.y;
    const float dL = powf(0.9f, (float)LCH);
    float a = 0.f;
    for (int cc=0; cc<c; ++cc) a = CARRY[((size_t)b*NC_ + cc)*D_ + d] + dL*a;
    const float ss = SEQ[b*D_ + d];
    float dp = powf(0.9f, (float)(c*LCH + 1));
    const u16* xp = X + ((size_t)(b*T_ + c*LCH))*D_ + d;
    float* op = OUT + ((size_t)(b*T_ + c*LCH))*D_ + d;
    for (int t=0;t<LCH;++t){
        a = 0.9f*a + bfu(xp[(size_t)t*D_]);
        op[(size_t)t*D_] = fmaf(ss, dp, a);
        dp *= 0.9f;
    }
}

// ---------------------------------------------------------------------------
// LayerNorms
// ---------------------------------------------------------------------------
__global__ __launch_bounds__(256) void ln_k(const float* __restrict__ in,
    const float* __restrict__ g, const float* __restrict__ b,
    float* __restrict__ out, u16* __restrict__ out2)
{
    int row  = blockIdx.x*4 + (threadIdx.x>>6);
    int lane = threadIdx.x & 63;
    const float* ip = in + (size_t)row*D_ + lane*4;
    float4 x = *(const float4*)ip;
    float s  = x.x+x.y+x.z+x.w;
    float s2 = x.x*x.x + x.y*x.y + x.z*x.z + x.w*x.w;
    #pragma unroll
    for (int o=1;o<64;o<<=1){ s += __shfl_xor(s,o); s2 += __shfl_xor(s2,o); }
    float mean = s * (1.f/256.f);
    float var  = s2 * (1.f/256.f) - mean*mean;
    float rs = rsqrtf(var + 1e-5f);
    int db = lane*4;
    float4 r;
    r.x=(x.x-mean)*rs*g[db+0]+b[db+0];
    r.y=(x.y-mean)*rs*g[db+1]+b[db+1];
    r.z=(x.z-mean)*rs*g[db+2]+b[db+2];
    r.w=(x.w-mean)*rs*g[db+3]+b[db+3];
    if (out)
        *(float4*)(out + (size_t)row*D_ + db) = r;
    if (out2)
        *(uint2*)(out2 + (size_t)row*D_ + db) = (uint2){ pk2(r.x,r.y), pk2(r.z,r.w) };
}

__global__ __launch_bounds__(256) void ln3_k(const float* __restrict__ in,
    const float* __restrict__ g3, const float* __restrict__ b3, u16* __restrict__ states,
    const float* __restrict__ g4, const float* __restrict__ b4, float* __restrict__ fsout)
{
    int row  = blockIdx.x*4 + (threadIdx.x>>6);
    int lane = threadIdx.x & 63;
    const float* ip = in + (size_t)row*D_ + lane*4;
    float4 x = *(const float4*)ip;
    float s  = x.x+x.y+x.z+x.w;
    float s2 = x.x*x.x + x.y*x.y + x.z*x.z + x.w*x.w;
    #pragma unroll
    for (int o=1;o<64;o<<=1){ s += __shfl_xor(s,o); s2 += __shfl_xor(s2,o); }
    float mean = s * (1.f/256.f);
    float var  = s2 * (1.f/256.f) - mean*mean;
    float rs = rsqrtf(var + 1e-5f);
    int db = lane*4;
    float4 st;
    st.x=(x.x-mean)*rs*g3[db+0]+b3[db+0];
    st.y=(x.y-mean)*rs*g3[db+1]+b3[db+1];
    st.z=(x.z-mean)*rs*g3[db+2]+b3[db+2];
    st.w=(x.w-mean)*rs*g3[db+3]+b3[db+3];
    *(uint2*)(states + (size_t)row*D_ + db) = (uint2){ pk2(st.x,st.y), pk2(st.z,st.w) };

    if ((row & (T_-1)) == T_-1){
        float u  = st.x+st.y+st.z+st.w;
        float u2 = st.x*st.x + st.y*st.y + st.z*st.z + st.w*st.w;
        #pragma unroll
        for (int o=1;o<64;o<<=1){ u += __shfl_xor(u,o); u2 += __shfl_xor(u2,o); }
        float m2 = u * (1.f/256.f);
        float v2 = u2 * (1.f/256.f) - m2*m2;
        float r2 = rsqrtf(v2 + 1e-5f);
        float4 fs;
        fs.x=(st.x-m2)*r2*g4[db+0]+b4[db+0];
        fs.y=(st.y-m2)*r2*g4[db+1]+b4[db+1];
        fs.z=(st.z-m2)*r2*g4[db+2]+b4[db+2];
        fs.w=(st.w-m2)*r2*g4[db+3]+b4[db+3];
        *(float4*)(fsout + (size_t)(row>>11)*D_ + db) = fs;
    }
}

// ---------------------------------------------------------------------------
extern "C" void kernel_launch(void* const* d_in, const int* in_sizes, int n_in,
                              void* d_out, int out_size, void* d_ws, size_t ws_size,
                              hipStream_t stream)
{
    const float* X     = (const float*)d_in[0];
    const float* SEQ   = (const float*)d_in[1];
    const float* conv_w= (const float*)d_in[3];
    const float* conv_b= (const float*)d_in[4];
    const float* qkv_w = (const float*)d_in[5];
    const float* qkv_b = (const float*)d_in[6];
    const float* mo_w  = (const float*)d_in[7];
    const float* mo_b  = (const float*)d_in[8];
    const float* fg_w  = (const float*)d_in[9];
    const float* fg_b  = (const float*)d_in[10];
    const float* gkv_w = (const float*)d_in[11];
    const float* gkv_b = (const float*)d_in[12];
    const float* go_w  = (const float*)d_in[13];
    const float* go_b  = (const float*)d_in[14];
    const float* comb_w= (const float*)d_in[15];
    const float* comb_b= (const float*)d_in[16];
    const float* ffn1_w= (const float*)d_in[17];
    const float* ffn1_b= (const float*)d_in[18];
    const float* ffn2_w= (const float*)d_in[19];
    const float* ffn2_b= (const float*)d_in[20];
    const float* tr1_w = (const float*)d_in[21];
    const float* tr1_b = (const float*)d_in[22];
    const float* tr2_w = (const float*)d_in[23];
    const float* tr2_b = (const float*)d_in[24];
    const float* p2s_w = (const float*)d_in[25];
    const float* p2s_b = (const float*)d_in[26];
    const float* s2p_w = (const float*)d_in[27];
    const float* s2p_b = (const float*)d_in[28];
    const float* ln1_g = (const float*)d_in[29];
    const float* ln1_b = (const float*)d_in[30];
    const float* ln2_g = (const float*)d_in[31];
    const float* ln2_b = (const float*)d_in[32];
    const float* ln3_g = (const float*)d_in[33];
    const float* ln3_b = (const float*)d_in[34];
    const float* ln4_g = (const float*)d_in[35];
    const float* ln4_b = (const float*)d_in[36];

    // -------- workspace carve (256-byte aligned chunks) --------
    char* p = (char*)d_ws;
    auto alloc = [&](size_t bytes)->char*{ char* r = p; p += (bytes + 255) & ~(size_t)255; return r; };

    u16*   QKVG = (u16*)  alloc((size_t)M_*1280*2);
    u16*   Wh   = (u16*)  alloc((size_t)NWELEM*2);
    float* bq   = (float*)alloc(1280*4);
    u16*   Xh   = (u16*)  alloc((size_t)M_*256*2);
    u16*   MED  = (u16*)  alloc((size_t)M_*256*2);
    u16*   MED2 = (u16*)  alloc((size_t)M_*256*2);
    u16*   LH   = (u16*)  alloc((size_t)M_*256*2);
    u16*   CONC = (u16*)  alloc((size_t)M_*256*2);
    u16*   GOUT = (u16*)  alloc((size_t)M_*256*2);
    u16*   MOUT = (u16*)  alloc((size_t)M_*256*2);
    float* PRE1 = (float*)alloc((size_t)M_*256*4);
    u16*   PRh  = (u16*)  alloc((size_t)M_*256*2);
    u16*   GSUM = (u16*)  alloc((size_t)M_*256*2);
    u16*   CS1  = (u16*)  alloc((size_t)M_*256*2);
    u16*   H1   = (u16*)  alloc((size_t)M_*512*2);
    u16*   SCALEDh=(u16*) alloc((size_t)M_*256*2);
    float* PRE3 = (float*)alloc((size_t)M_*256*4);
    u16*   STATESh=(u16*) alloc((size_t)M_*256*2);
    u16*   FFNIN= (u16*)  alloc((size_t)M_*256*2);
    u16*   H2   = (u16*)  alloc((size_t)M_*1024*2);
    float* PRE2 = (float*)alloc((size_t)M_*256*4);
    float* CAR0 = (float*)alloc((size_t)B_*NC_*D_*4);
    float* CAR1 = (float*)alloc((size_t)B_*NC_*D_*4);

    float* out_pr = (float*)d_out;
    float* out_fs = out_pr + (size_t)M_*256;
    float* out_tj = out_fs + B_*256;

    const dim3 blk256(256), blk512(512);
    const dim3 scan_grid(NC_, B_);
    const int NRg = M_/128;   // 64 row tiles

    // 0. convert weights + X to bf16, concat qkv/gkv bias
    cvt_k<<<dim3(3842), blk256, 0, stream>>>(
        qkv_w, gkv_w, qkv_b, gkv_b, mo_w, fg_w, go_w, comb_w,
        ffn1_w, ffn2_w, tr1_w, tr2_w, p2s_w, s2p_w, X, Wh, Xh, bq);
    // 1. fused qkv+gkv projection -> QKVG (bf16)
    gemm_k<<<dim3(NRg*20), blk512, 0, stream>>>(
        Xh, Wh+OFF_QKV, 256, 256,  nullptr,nullptr,0,0,  nullptr,nullptr,0,0,
        bq, nullptr, 0, QKVG, 1280, 1, OP_NONE, 20);
    // 2. local_history (depthwise conv) -> LH bf16
    conv_k<<<dim3(M_*D_/1024), blk256, 0, stream>>>(Xh, conv_w, conv_b, LH);
    // 3. banded attention (MFMA, V transposed in-LDS) -> MED bf16
    attn_k<<<dim3(T_/64, H_, B_), blk256, 0, stream>>>(QKVG, MED);
    // 4. mo projection -> MED2 bf16
    gemm_k<<<dim3(NRg*4), blk512, 0, stream>>>(
        MED, Wh+OFF_MO, 256, 256,  nullptr,nullptr,0,0,  nullptr,nullptr,0,0,
        mo_b, nullptr, 0, MED2, 256, 1, OP_NONE, 4);
    // 5. concepts scan -> CONC bf16
    scan1_p1<<<scan_grid, blk256, 0, stream>>>(QKVG, CAR0, CAR1);
    scan1_p3<<<scan_grid, blk256, 0, stream>>>(QKVG, CAR0, CAR1, CONC);
    // 6. global_out -> GOUT bf16
    gemm_k<<<dim3(NRg*4), blk512, 0, stream>>>(
        CONC, Wh+OFF_GO, 256, 256,  nullptr,nullptr,0,0,  nullptr,nullptr,0,0,
        go_b, nullptr, 0, GOUT, 256, 1, OP_NONE, 4);
    // 7. medium_out = MED2 * sigmoid([X,MED2]@fg^T + b) -> MOUT bf16
    gemm_k<<<dim3(NRg*4), blk512, 0, stream>>>(
        Xh, Wh+OFF_FG, 512, 256,  MED2, Wh+OFF_FG+256, 512, 256,  nullptr,nullptr,0,0,
        fg_b, MED2, 1, MOUT, 256, 1, OP_SIGMUL, 4);
    // 8. pre_ln1 = X + [LH,MOUT,GOUT]@comb^T + b -> PRE1 fp32
    gemm_k<<<dim3(NRg*4), blk512, 0, stream>>>(
        LH, Wh+OFF_COMB, 768, 256,  MOUT, Wh+OFF_COMB+256, 768, 256,  GOUT, Wh+OFF_COMB+512, 768, 256,
        comb_b, X, 0, PRE1, 256, 0, OP_ADDAUX, 4);
    // 9. pr = LN1 -> PRh bf16 only
    ln_k<<<dim3(M_/4), blk256, 0, stream>>>(PRE1, ln1_g, ln1_b, nullptr, PRh);
    // 10. global_summary EMA -> GSUM bf16, final_traj -> out
    ema_p1h<<<scan_grid, blk256, 0, stream>>>(PRh, CAR0, 0.1f);
    ema_p3h<<<scan_grid, blk256, 0, stream>>>(PRh, CAR0, GSUM, 0.1f, out_tj);
    // 11. cs1 = pr + 0.3*(pr@p2s^T + b) -> CS1 bf16
    gemm_k<<<dim3(NRg*4), blk512, 0, stream>>>(
        PRh, Wh+OFF_P2S, 256, 256,  nullptr,nullptr,0,0,  nullptr,nullptr,0,0,
        p2s_b, PRh, 1, CS1, 256, 1, OP_AXPBY, 4);
    // 12. H1 = gelu(cs1@tr1a + gsum@tr1b + b) bf16
    gemm_k<<<dim3(NRg*8), blk512, 0, stream>>>(
        CS1, Wh+OFF_TR1, 512, 256,  GSUM, Wh+OFF_TR1+256, 512, 256,  nullptr,nullptr,0,0,
        tr1_b, nullptr, 0, H1, 512, 1, OP_GELU, 8);
    // 13. scaled = 0.5*tanh(H1@tr2^T + b) -> SCALEDh bf16
    gemm_k<<<dim3(NRg*4), blk512, 0, stream>>>(
        H1, Wh+OFF_TR2, 512, 512,  nullptr,nullptr,0,0,  nullptr,nullptr,0,0,
        tr2_b, nullptr, 0, SCALEDh, 256, 1, OP_TANHHALF, 4);
    // 14. state EMA + decayed initial -> PRE3 fp32
    ema_p1h<<<scan_grid, blk256, 0, stream>>>(SCALEDh, CAR0, 1.0f);
    ema_p3_state_h<<<scan_grid, blk256, 0, stream>>>(SCALEDh, CAR0, SEQ, PRE3);
    // 15. states = LN3 -> STATESh bf16; final_state = LN4(states[-1]) -> out
    ln3_k<<<dim3(M_/4), blk256, 0, stream>>>(PRE3, ln3_g, ln3_b, STATESh, ln4_g, ln4_b, out_fs);
    // 16. ffn_in = pr + 0.3*(states@s2p^T + b) -> FFNIN bf16
    gemm_k<<<dim3(NRg*4), blk512, 0, stream>>>(
        STATESh, Wh+OFF_S2P, 256, 256,  nullptr,nullptr,0,0,  nullptr,nullptr,0,0,
        s2p_b, PRh, 1, FFNIN, 256, 1, OP_AXPBY, 4);
    // 17. H2 = gelu(ffn_in@ffn1^T + b) bf16
    gemm_k<<<dim3(NRg*16), blk512, 0, stream>>>(
        FFNIN, Wh+OFF_FFN1, 256, 256,  nullptr,nullptr,0,0,  nullptr,nullptr,0,0,
        ffn1_b, nullptr, 0, H2, 1024, 1, OP_GELU, 16);
    // 18. pre_ln2 = pr + H2@ffn2^T + b -> PRE2 fp32
    gemm_k<<<dim3(NRg*4), blk512, 0, stream>>>(
        H2, Wh+OFF_FFN2, 1024, 1024,  nullptr,nullptr,0,0,  nullptr,nullptr,0,0,
        ffn2_b, PRh, 1, PRE2, 256, 0, OP_ADDAUX, 4);
    // 19. pr_out = LN2 -> d_out
    ln_k<<<dim3(M_/4), blk256, 0, stream>>>(PRE2, ln2_g, ln2_b, out_pr, nullptr);
}